// Round 2
// baseline (33281.931 us; speedup 1.0000x reference)
//
#include <hip/hip_runtime.h>
#include <math.h>

#define DEV __device__ __forceinline__

DEV float gelu_f(float v) { return 0.5f * v * (1.0f + erff(v * 0.70710678118654752f)); }
DEV float sigm_f(float v) { return 1.0f / (1.0f + expf(-v)); }

// ---------------------------------------------------------------------------
// Encoder conv1 (chunked): 1ch 64x64 stride2 -> 32ch 32x32, reads concat(x,t)
// base = first global image index of this chunk; out is chunk-local.
// ---------------------------------------------------------------------------
__global__ __launch_bounds__(256) void ec1_k(
    const float* __restrict__ x, const float* __restrict__ t,
    const float* __restrict__ w, const float* __restrict__ bias,
    float* __restrict__ out, int base)
{
  int idx = blockIdx.x * 256 + threadIdx.x;          // < 256*32*32*32
  int ow = idx & 31;
  int oh = (idx >> 5) & 31;
  int co = (idx >> 10) & 31;
  int nl = idx >> 15;                                 // local image 0..255
  int n  = base + nl;                                 // global image 0..1023
  int b = n >> 5, j = n & 31;
  const float* ip = (j < 16) ? (x + (size_t)(b * 16 + j) * 4096)
                             : (t + (size_t)(b * 16 + j - 16) * 4096);
  const float* wp = w + co * 9;
  float acc = bias[co];
#pragma unroll
  for (int kh = 0; kh < 3; ++kh) {
    int ih = oh * 2 + kh - 1;
    if ((unsigned)ih < 64u) {
#pragma unroll
      for (int kw = 0; kw < 3; ++kw) {
        int iw = ow * 2 + kw - 1;
        if ((unsigned)iw < 64u)
          acc = fmaf(ip[ih * 64 + iw], wp[kh * 3 + kw], acc);
      }
    }
  }
  out[idx] = gelu_f(acc);
}

// ---------------------------------------------------------------------------
// Generic direct 3x3 conv, pad 1, NCHW, OIHW weights. Chunk-transparent:
// caller passes chunk-offset in/out pointers and sizes grid for NIMG images.
// ---------------------------------------------------------------------------
template<int CIN, int COUT, int S, int HIN, int WIN, bool DOGELU>
__global__ __launch_bounds__(256) void conv3x3_k(
    const float* __restrict__ in, const float* __restrict__ w,
    const float* __restrict__ bias, float* __restrict__ out)
{
  constexpr int HO = HIN / S, WO = WIN / S;
  int idx = blockIdx.x * 256 + threadIdx.x;
  int ow = idx % WO;
  int oh = (idx / WO) % HO;
  int co = (idx / (WO * HO)) % COUT;
  int n  = idx / (WO * HO * COUT);
  const float* ip = in + (size_t)n * CIN * HIN * WIN;
  const float* wp = w + co * CIN * 9;
  float acc = bias[co];
  for (int ci = 0; ci < CIN; ++ci) {
    const float* ipc = ip + ci * HIN * WIN;
    const float* wpc = wp + ci * 9;
#pragma unroll
    for (int kh = 0; kh < 3; ++kh) {
      int ih = oh * S + kh - 1;
      if ((unsigned)ih < (unsigned)HIN) {
#pragma unroll
        for (int kw = 0; kw < 3; ++kw) {
          int iw = ow * S + kw - 1;
          if ((unsigned)iw < (unsigned)WIN)
            acc = fmaf(ipc[ih * WIN + iw], wpc[kh * 3 + kw], acc);
        }
      }
    }
  }
  out[idx] = DOGELU ? gelu_f(acc) : acc;
}

// ---------------------------------------------------------------------------
// Transposed conv 3x3, stride(2) via lhs_dilation=2, pad(1,2): HIN -> 2*HIN
// w layout (CIN, COUT, 3, 3), tap w[ci][co][2-kh][2-kw]. Chunk-transparent.
// ---------------------------------------------------------------------------
template<int CIN, int COUT, int HIN, int WIN, bool DOGELU>
__global__ __launch_bounds__(256) void tconv3x3_k(
    const float* __restrict__ in, const float* __restrict__ w,
    const float* __restrict__ bias, float* __restrict__ out)
{
  constexpr int HO = 2 * HIN, WO = 2 * WIN;
  int idx = blockIdx.x * 256 + threadIdx.x;
  int q  = idx % WO;
  int p  = (idx / WO) % HO;
  int co = (idx / (WO * HO)) % COUT;
  int n  = idx / (WO * HO * COUT);
  const float* ip = in + (size_t)n * CIN * HIN * WIN;
  float acc = bias[co];
  for (int ci = 0; ci < CIN; ++ci) {
    const float* ipc = ip + ci * HIN * WIN;
    const float* wpc = w + (ci * COUT + co) * 9;
#pragma unroll
    for (int kh = 0; kh < 3; ++kh) {
      int u = p + kh - 1;
      if (u >= 0 && !(u & 1) && (u >> 1) < HIN) {
#pragma unroll
        for (int kw = 0; kw < 3; ++kw) {
          int v = q + kw - 1;
          if (v >= 0 && !(v & 1) && (v >> 1) < WIN)
            acc = fmaf(ipc[(u >> 1) * WIN + (v >> 1)], wpc[(2 - kh) * 3 + (2 - kw)], acc);
        }
      }
    }
  }
  out[idx] = DOGELU ? gelu_f(acc) : acc;
}

// ---------------------------------------------------------------------------
// Final tconv 32->1 (32x32 -> 64x64) + tanh + fused loss partials, chunked.
// Global image n = base + local n. n<512: pred branch (store d_out, vs t);
// n>=512: rec branch (vs x). partials pointer is pre-offset by caller.
// ---------------------------------------------------------------------------
__global__ __launch_bounds__(256) void dt3_loss_k(
    const float* __restrict__ in,   // (256,32,32,32) chunk-local
    const float* __restrict__ w,    // (32,1,3,3)
    const float* __restrict__ bias, // (1)
    const float* __restrict__ xref, // (512,4096)
    const float* __restrict__ tref, // (512,4096)
    float* __restrict__ fout,       // d_out+2
    float* __restrict__ partials,   // pre-offset, 4096 per chunk
    int base)
{
  constexpr int CIN = 32, HIN = 32, WIN = 32;
  int idx = blockIdx.x * 256 + threadIdx.x;
  int q = idx & 63;
  int p = (idx >> 6) & 63;
  int nl = idx >> 12;
  int n = base + nl;
  const float* ip = in + (size_t)nl * CIN * HIN * WIN;
  float acc = bias[0];
  for (int ci = 0; ci < CIN; ++ci) {
    const float* ipc = ip + ci * (HIN * WIN);
    const float* wpc = w + ci * 9;
#pragma unroll
    for (int kh = 0; kh < 3; ++kh) {
      int u = p + kh - 1;
      if (u >= 0 && !(u & 1) && (u >> 1) < HIN) {
#pragma unroll
        for (int kw = 0; kw < 3; ++kw) {
          int v = q + kw - 1;
          if (v >= 0 && !(v & 1) && (v >> 1) < WIN)
            acc = fmaf(ipc[(u >> 1) * WIN + (v >> 1)], wpc[(2 - kh) * 3 + (2 - kw)], acc);
        }
      }
    }
  }
  float val = tanhf(acc);
  float d;
  int pix = p * 64 + q;
  if (n < 512) {
    fout[(size_t)n * 4096 + pix] = val;
    d = val - tref[(size_t)n * 4096 + pix];
  } else {
    d = val - xref[(size_t)(n - 512) * 4096 + pix];
  }
  float sq = d * d;
  __shared__ float red[256];
  red[threadIdx.x] = sq;
  __syncthreads();
#pragma unroll
  for (int s = 128; s > 0; s >>= 1) {
    if (threadIdx.x < s) red[threadIdx.x] += red[threadIdx.x + s];
    __syncthreads();
  }
  if (threadIdx.x == 0) partials[blockIdx.x] = red[0];
}

__global__ __launch_bounds__(256) void loss_final_k(
    const float* __restrict__ partials, float* __restrict__ out01)
{
  __shared__ float red[256];
  int base = blockIdx.x * 8192;        // block 0: pred, block 1: rec
  float s = 0.f;
  for (int i = threadIdx.x; i < 8192; i += 256) s += partials[base + i];
  red[threadIdx.x] = s;
  __syncthreads();
#pragma unroll
  for (int st = 128; st > 0; st >>= 1) {
    if (threadIdx.x < st) red[threadIdx.x] += red[threadIdx.x + st];
    __syncthreads();
  }
  if (threadIdx.x == 0) out01[blockIdx.x] = red[0] * (1.0f / 2097152.0f);
}

// ---------------------------------------------------------------------------
// fp32 tiled GEMM: C[m,n] = sum_k A[m,k]*B[n,k] + bias[n]  (B is (N,K) row-major)
// tile 64x64, BK=16, 256 threads, 4x4 micro-tile
// ---------------------------------------------------------------------------
template<bool DOGELU>
__global__ __launch_bounds__(256) void gemm_bt_k(
    const float* __restrict__ A, const float* __restrict__ B,
    const float* __restrict__ bias, float* __restrict__ C,
    int M, int N, int K)
{
  __shared__ float As[16][68];
  __shared__ float Bs[16][68];
  const int tid = threadIdx.x;
  const int tx = tid & 15, ty = tid >> 4;
  const int rowBlk = blockIdx.y * 64, colBlk = blockIdx.x * 64;
  float acc[4][4] = {};
  for (int k0 = 0; k0 < K; k0 += 16) {
#pragma unroll
    for (int j = 0; j < 4; ++j) {
      int f = tid + j * 256;
      int m = f >> 4, kk = f & 15;
      As[kk][m] = A[(size_t)(rowBlk + m) * K + k0 + kk];
      Bs[kk][m] = B[(size_t)(colBlk + m) * K + k0 + kk];
    }
    __syncthreads();
#pragma unroll
    for (int kk = 0; kk < 16; ++kk) {
      float4 a4 = *(const float4*)&As[kk][ty * 4];
      float4 b4 = *(const float4*)&Bs[kk][tx * 4];
      float av[4] = {a4.x, a4.y, a4.z, a4.w};
      float bv[4] = {b4.x, b4.y, b4.z, b4.w};
#pragma unroll
      for (int i = 0; i < 4; ++i)
#pragma unroll
        for (int j = 0; j < 4; ++j) acc[i][j] = fmaf(av[i], bv[j], acc[i][j]);
    }
    __syncthreads();
  }
#pragma unroll
  for (int i = 0; i < 4; ++i) {
    int row = rowBlk + ty * 4 + i;
#pragma unroll
    for (int j = 0; j < 4; ++j) {
      int col = colBlk + tx * 4 + j;
      float v = acc[i][j] + bias[col];
      C[(size_t)row * N + col] = DOGELU ? gelu_f(v) : v;
    }
  }
}

// ---------------------------------------------------------------------------
// LSTM: persistent cooperative kernel. 128 blocks x 256 threads.
// Block w owns columns j = {2w, 2w+1}. Thread: jj=tid>>7, g=(tid>>5)&3, b=tid&31.
// One grid barrier per cell. h double-buffered by t parity.
// ---------------------------------------------------------------------------
#define LSTM_NB 128

DEV void gridbar(unsigned* bar, unsigned target) {
  __syncthreads();
  if (threadIdx.x == 0) {
    __hip_atomic_fetch_add(bar, 1u, __ATOMIC_RELEASE, __HIP_MEMORY_SCOPE_AGENT);
    unsigned spins = 0;
    while (__hip_atomic_load(bar, __ATOMIC_RELAXED, __HIP_MEMORY_SCOPE_AGENT) < target) {
      __builtin_amdgcn_s_sleep(8);
      if (++spins > (1u << 22)) break;   // safety valve: never hang forever
    }
    (void)__hip_atomic_load(bar, __ATOMIC_ACQUIRE, __HIP_MEMORY_SCOPE_AGENT);
  }
  __syncthreads();
}

__global__ __launch_bounds__(256, 2) void lstm_k(
    const float* __restrict__ z,    // (1024,256) encoder latents, row = b*32+t
    const float* __restrict__ Wih,  // (10,1024,256)
    const float* __restrict__ Whh,  // (10,1024,256)
    const float* __restrict__ bih,  // (10,1024)
    const float* __restrict__ bhh,  // (10,1024)
    const float* __restrict__ lw,   // (256,256)
    const float* __restrict__ lb,   // (256)
    float* __restrict__ h,          // (2,10,32,256)
    float* __restrict__ c,          // (10,32,256)
    float* __restrict__ outs,       // (31,32,256)
    unsigned* __restrict__ bar)
{
  __shared__ float s_wih[8][256];
  __shared__ float s_whh[8][256];
  __shared__ float s_zg[2][4][32];
  const int wg  = blockIdx.x;          // 0..127
  const int tid = threadIdx.x;
  const int b   = tid & 31;
  const int g   = (tid >> 5) & 3;
  const int jj  = tid >> 7;
  const int j   = 2 * wg + jj;
  const int r   = (g << 1) | jj;
  const int n   = g * 256 + j;
  unsigned ep = 0;

  for (int i = wg * 256 + tid; i < 2 * 10 * 32 * 256; i += LSTM_NB * 256) h[i] = 0.f;
  for (int i = wg * 256 + tid; i < 10 * 32 * 256;     i += LSTM_NB * 256) c[i] = 0.f;
  ++ep; gridbar(bar, ep * LSTM_NB);

  for (int t = 0; t < 31; ++t) {
    const int cur = t & 1, prv = cur ^ 1;
    const float* xrow0 = (t < 16) ? (z + (size_t)(b * 32 + t) * 256)
                                  : (outs + (size_t)((t - 1) * 32 + b) * 256);
    for (int l = 0; l < 10; ++l) {
      const float* wihl = Wih + (size_t)l * 1024 * 256;
      const float* whhl = Whh + (size_t)l * 1024 * 256;
#pragma unroll
      for (int i = 0; i < 8; ++i) {
        int f  = tid + i * 256;                 // 0..2047
        int rr = f >> 8, k = f & 255;
        int nr = (rr >> 1) * 256 + 2 * wg + (rr & 1);
        s_wih[rr][k] = wihl[(size_t)nr * 256 + k];
        s_whh[rr][k] = whhl[(size_t)nr * 256 + k];
      }
      __syncthreads();
      const float* xrow = (l == 0) ? xrow0
                                   : (h + (size_t)((cur * 10 + (l - 1)) * 32 + b) * 256);
      const float* hrow = h + (size_t)((prv * 10 + l) * 32 + b) * 256;
      float acc = bih[l * 1024 + n] + bhh[l * 1024 + n];
      const float4* x4  = (const float4*)xrow;
      const float4* h4  = (const float4*)hrow;
      const float4* wi4 = (const float4*)s_wih[r];
      const float4* wh4 = (const float4*)s_whh[r];
#pragma unroll 4
      for (int k = 0; k < 64; ++k) {
        float4 xa = x4[k], wa = wi4[k];
        acc = fmaf(xa.x, wa.x, acc); acc = fmaf(xa.y, wa.y, acc);
        acc = fmaf(xa.z, wa.z, acc); acc = fmaf(xa.w, wa.w, acc);
        float4 hb = h4[k], wb = wh4[k];
        acc = fmaf(hb.x, wb.x, acc); acc = fmaf(hb.y, wb.y, acc);
        acc = fmaf(hb.z, wb.z, acc); acc = fmaf(hb.w, wb.w, acc);
      }
      s_zg[jj][g][b] = acc;
      __syncthreads();
      if (g == 0) {
        float zi = s_zg[jj][0][b], zf = s_zg[jj][1][b];
        float zgg = s_zg[jj][2][b], zo = s_zg[jj][3][b];
        float* crow = c + (size_t)(l * 32 + b) * 256;
        float cold = crow[j];
        float cn = sigm_f(zf) * cold + sigm_f(zi) * tanhf(zgg);
        float hn = sigm_f(zo) * tanhf(cn);
        crow[j] = cn;
        h[(size_t)((cur * 10 + l) * 32 + b) * 256 + j] = hn;
      }
      ++ep; gridbar(bar, ep * LSTM_NB);
    }
    if (t >= 15) {
      if (g == 0) {
        const float* h9  = h + (size_t)((cur * 10 + 9) * 32 + b) * 256;
        const float* lwr = lw + j * 256;
        float acc = lb[j];
        const float4* a4 = (const float4*)h9;
        const float4* w4 = (const float4*)lwr;
#pragma unroll 4
        for (int k = 0; k < 64; ++k) {
          float4 xa = a4[k], wa = w4[k];
          acc = fmaf(xa.x, wa.x, acc); acc = fmaf(xa.y, wa.y, acc);
          acc = fmaf(xa.z, wa.z, acc); acc = fmaf(xa.w, wa.w, acc);
        }
        outs[(size_t)(t * 32 + b) * 256 + j] = acc;
      }
      ++ep; gridbar(bar, ep * LSTM_NB);
    }
  }
}

// ---------------------------------------------------------------------------
// Build decoder input: rows 0..511 = y_t (outs[15+i][b]), rows 512..1023 = z_x
// ---------------------------------------------------------------------------
__global__ __launch_bounds__(256) void gather_dec_k(
    const float* __restrict__ outs, const float* __restrict__ z,
    float* __restrict__ ydec)
{
  int idx = blockIdx.x * 256 + threadIdx.x;   // < 262144
  int rrow = idx >> 8, k = idx & 255;
  float v;
  if (rrow < 512) {
    int b = rrow >> 4, i = rrow & 15;
    v = outs[(size_t)((15 + i) * 32 + b) * 256 + k];
  } else {
    int rr = rrow - 512;
    int b = rr >> 4, tt = rr & 15;
    v = z[(size_t)(b * 32 + tt) * 256 + k];
  }
  ydec[idx] = v;
}

// ---------------------------------------------------------------------------
extern "C" void kernel_launch(void* const* d_in, const int* in_sizes, int n_in,
                              void* d_out, int out_size, void* d_ws, size_t ws_size,
                              hipStream_t stream) {
  const float* x     = (const float*)d_in[0];
  const float* t     = (const float*)d_in[1];
  const float* ec1_w = (const float*)d_in[2];
  const float* ec1_b = (const float*)d_in[3];
  const float* ec2_w = (const float*)d_in[4];
  const float* ec2_b = (const float*)d_in[5];
  const float* ec3_w = (const float*)d_in[6];
  const float* ec3_b = (const float*)d_in[7];
  const float* ec4_w = (const float*)d_in[8];
  const float* ec4_b = (const float*)d_in[9];
  const float* ec5_w = (const float*)d_in[10];
  const float* ec5_b = (const float*)d_in[11];
  const float* el_w  = (const float*)d_in[12];
  const float* el_b  = (const float*)d_in[13];
  const float* dl_w  = (const float*)d_in[14];
  const float* dl_b  = (const float*)d_in[15];
  const float* dt1_w = (const float*)d_in[16];
  const float* dt1_b = (const float*)d_in[17];
  const float* dc1_w = (const float*)d_in[18];
  const float* dc1_b = (const float*)d_in[19];
  const float* dt2_w = (const float*)d_in[20];
  const float* dt2_b = (const float*)d_in[21];
  const float* dc2_w = (const float*)d_in[22];
  const float* dc2_b = (const float*)d_in[23];
  const float* dt3_w = (const float*)d_in[24];
  const float* dt3_b = (const float*)d_in[25];
  const float* Wih   = (const float*)d_in[26];
  const float* Whh   = (const float*)d_in[27];
  const float* bih   = (const float*)d_in[28];
  const float* bhh   = (const float*)d_in[29];
  const float* lw    = (const float*)d_in[30];
  const float* lb    = (const float*)d_in[31];
  float* out = (float*)d_out;

  char* base = (char*)d_ws;
  size_t off = 0;
  auto alloc = [&](size_t bytes) -> char* {
    char* p = base + off;
    off += (bytes + 255) & ~(size_t)255;
    return p;
  };
  // total ~88 MB
  unsigned* bar   = (unsigned*)alloc(256);
  float* zbuf     = (float*)alloc((size_t)1024 * 256 * 4);           // 1 MB
  float* hbuf     = (float*)alloc((size_t)2 * 10 * 32 * 256 * 4);
  float* cbuf     = (float*)alloc((size_t)10 * 32 * 256 * 4);
  float* outsbuf  = (float*)alloc((size_t)31 * 32 * 256 * 4);
  float* ydec     = (float*)alloc((size_t)1024 * 256 * 4);           // 1 MB
  float* partials = (float*)alloc((size_t)16384 * 4);
  float* enc5buf  = (float*)alloc((size_t)1024 * 4096 * 4);          // 16.8 MB
  float* bufA     = (float*)alloc((size_t)256 * 32 * 32 * 32 * 4);   // 33.5 MB
  float* bufB     = (float*)alloc((size_t)256 * 32 * 32 * 32 * 4);   // 33.5 MB
  (void)in_sizes; (void)n_in; (void)out_size; (void)ws_size;

  hipMemsetAsync(bar, 0, 8, stream);

  // ---- encoder: 4 chunks of 256 images ----
  for (int ch = 0; ch < 4; ++ch) {
    ec1_k<<<32768, 256, 0, stream>>>(x, t, ec1_w, ec1_b, bufA, ch * 256);
    conv3x3_k<32, 32, 1, 32, 32, true><<<32768, 256, 0, stream>>>(bufA, ec2_w, ec2_b, bufB);
    conv3x3_k<32, 64, 2, 32, 32, true><<<16384, 256, 0, stream>>>(bufB, ec3_w, ec3_b, bufA);
    conv3x3_k<64, 64, 1, 16, 16, true><<<16384, 256, 0, stream>>>(bufA, ec4_w, ec4_b, bufB);
    conv3x3_k<64, 64, 2, 16, 16, true><<<4096, 256, 0, stream>>>(
        bufB, ec5_w, ec5_b, enc5buf + (size_t)ch * 256 * 4096);
  }
  gemm_bt_k<false><<<dim3(4, 16), 256, 0, stream>>>(enc5buf, el_w, el_b, zbuf, 1024, 256, 4096);

  // ---- LSTM (persistent, grid-barriered) ----
  lstm_k<<<LSTM_NB, 256, 0, stream>>>(zbuf, Wih, Whh, bih, bhh, lw, lb,
                                      hbuf, cbuf, outsbuf, bar);

  // ---- decoder: 4 chunks of 256 rows (0,1 = pred; 2,3 = rec) ----
  gather_dec_k<<<1024, 256, 0, stream>>>(outsbuf, zbuf, ydec);
  for (int ch = 0; ch < 4; ++ch) {
    gemm_bt_k<true><<<dim3(64, 4), 256, 0, stream>>>(
        ydec + (size_t)ch * 256 * 256, dl_w, dl_b, bufB, 256, 4096, 256);
    tconv3x3_k<64, 64, 8, 8, true><<<16384, 256, 0, stream>>>(bufB, dt1_w, dt1_b, bufA);
    conv3x3_k<64, 64, 1, 16, 16, true><<<16384, 256, 0, stream>>>(bufA, dc1_w, dc1_b, bufB);
    tconv3x3_k<64, 32, 16, 16, true><<<32768, 256, 0, stream>>>(bufB, dt2_w, dt2_b, bufA);
    conv3x3_k<32, 32, 1, 32, 32, true><<<32768, 256, 0, stream>>>(bufA, dc2_w, dc2_b, bufB);
    dt3_loss_k<<<4096, 256, 0, stream>>>(bufB, dt3_w, dt3_b, x, t, out + 2,
                                         partials + ch * 4096, ch * 256);
  }
  loss_final_k<<<2, 256, 0, stream>>>(partials, out);
}

// Round 3
// 8667.896 us; speedup vs baseline: 3.8397x; 3.8397x over previous
//
#include <hip/hip_runtime.h>
#include <math.h>

#define DEV __device__ __forceinline__

typedef __attribute__((ext_vector_type(8))) short bf8_t;   // 8 x bf16 (4 VGPR)
typedef __attribute__((ext_vector_type(4))) float f4_t;    // MFMA acc

DEV float gelu_f(float v) { return 0.5f * v * (1.0f + erff(v * 0.70710678118654752f)); }
DEV float sigm_f(float v) { return 1.0f / (1.0f + expf(-v)); }
DEV unsigned short f2bf(float f) {            // RNE float->bf16
  unsigned u = __float_as_uint(f);
  u = (u + 0x7FFFu + ((u >> 16) & 1u)) >> 16;
  return (unsigned short)u;
}
DEV float bf2f(unsigned short u) { return __uint_as_float((unsigned)u << 16); }

// ---------------------------------------------------------------------------
// Weight prep: conv weights -> bf16 [co][kh][kw][ci]; FLIP=1 for tconv
// ---------------------------------------------------------------------------
__global__ __launch_bounds__(256) void prepw_k(
    const float* __restrict__ w, unsigned short* __restrict__ wb,
    int COUT, int CIN, int FLIP)
{
  int idx = blockIdx.x * 256 + threadIdx.x;
  int total = COUT * CIN * 9;
  if (idx >= total) return;
  int ci = idx % CIN;
  int r  = idx / CIN;
  int kw = r % 3; r /= 3;
  int kh = r % 3;
  int co = r / 3;
  float v = FLIP ? w[((ci * COUT + co) * 3 + (2 - kh)) * 3 + (2 - kw)]
                 : w[((co * CIN + ci) * 3 + kh) * 3 + kw];
  wb[idx] = f2bf(v);
}

// el_w (256,4096 k_ref=c*64+s) -> bf16 [n][k_new=(s*64+c)]
__global__ __launch_bounds__(256) void prep_el_k(
    const float* __restrict__ w, unsigned short* __restrict__ wb)
{
  int idx = blockIdx.x * 256 + threadIdx.x;     // < 256*4096
  int kn = idx & 4095, n = idx >> 12;
  wb[idx] = f2bf(w[(size_t)n * 4096 + ((kn & 63) * 64 + (kn >> 6))]);
}

// dl_w (4096,256) row r=c*64+s -> bf16 rows nout=s*64+c
__global__ __launch_bounds__(256) void prep_dl_k(
    const float* __restrict__ w, unsigned short* __restrict__ wb)
{
  int idx = blockIdx.x * 256 + threadIdx.x;     // < 4096*256
  int k = idx & 255, nout = idx >> 8;
  wb[idx] = f2bf(w[(size_t)((nout & 63) * 64 + (nout >> 6)) * 256 + k]);
}

// ---------------------------------------------------------------------------
// ec1: 1ch 64x64 s2 -> 32ch 32x32, NHWC bf16 out. base=chunk img offset.
// ---------------------------------------------------------------------------
__global__ __launch_bounds__(256) void ec1_k(
    const float* __restrict__ x, const float* __restrict__ t,
    const float* __restrict__ w, const float* __restrict__ bias,
    unsigned short* __restrict__ out, int base)
{
  __shared__ float sw[288];
  __shared__ float sb[32];
  for (int i = threadIdx.x; i < 288; i += 256) sw[i] = w[i];
  if (threadIdx.x < 32) sb[threadIdx.x] = bias[threadIdx.x];
  __syncthreads();
  int idx = blockIdx.x * 256 + threadIdx.x;     // < 512*32*32
  int ox = idx & 31, oy = (idx >> 5) & 31, nl = idx >> 10;
  int n = base + nl;
  int b = n >> 5, j = n & 31;
  const float* ip = (j < 16) ? (x + (size_t)(b * 16 + j) * 4096)
                             : (t + (size_t)(b * 16 + j - 16) * 4096);
  float pv[9];
#pragma unroll
  for (int kh = 0; kh < 3; ++kh) {
    int iy = oy * 2 + kh - 1;
#pragma unroll
    for (int kw = 0; kw < 3; ++kw) {
      int ix = ox * 2 + kw - 1;
      pv[kh * 3 + kw] = ((unsigned)iy < 64u && (unsigned)ix < 64u) ? ip[iy * 64 + ix] : 0.f;
    }
  }
  unsigned short u[32];
#pragma unroll
  for (int co = 0; co < 32; ++co) {
    float a = sb[co];
#pragma unroll
    for (int i = 0; i < 9; ++i) a = fmaf(pv[i], sw[co * 9 + i], a);
    u[co] = f2bf(gelu_f(a));
  }
  unsigned short* op = out + (size_t)idx * 32;
#pragma unroll
  for (int p = 0; p < 4; ++p) {
    uint4 v;
    v.x = u[p*8+0] | (u[p*8+1] << 16);
    v.y = u[p*8+2] | (u[p*8+3] << 16);
    v.z = u[p*8+4] | (u[p*8+5] << 16);
    v.w = u[p*8+6] | (u[p*8+7] << 16);
    *(uint4*)&op[p * 8] = v;
  }
}

// ---------------------------------------------------------------------------
// MFMA implicit-GEMM conv. NHWC bf16 in/out. MODE: 0=s1, 1=s2, 2=tconv(ups2).
// Weights wb: bf16 [co][kh][kw][ci] (pre-flipped for MODE 2).
// Block: 256 thr = 4 waves; one output tile TH x TW x COUT.
// LDS: input tile [tyy][cg][txx][8ci] bf16.
// ---------------------------------------------------------------------------
template<int CIN, int COUT, int HIN, int WIN, int TH, int TW, int MODE>
__global__ __launch_bounds__(256) void convmf_k(
    const unsigned short* __restrict__ in, const unsigned short* __restrict__ wb,
    const float* __restrict__ bias, unsigned short* __restrict__ out)
{
  constexpr int HO  = (MODE == 1) ? HIN / 2 : (MODE == 2 ? HIN * 2 : HIN);
  constexpr int WO  = (MODE == 1) ? WIN / 2 : (MODE == 2 ? WIN * 2 : WIN);
  constexpr int TIH = (MODE == 1) ? 2 * TH + 1 : TH + 2;
  constexpr int TIW = (MODE == 1) ? 2 * TW + 1 : TW + 2;
  constexpr int CG  = CIN / 8;
  constexpr int K   = 9 * CIN;
  constexpr int KS  = K / 32;
  constexpr int NT  = COUT / 16;
  constexpr int MT  = (TH * TW) / 16;
  constexpr int MPW = MT / 4;
  constexpr int TY  = HO / TH, TX = WO / TW;

  __shared__ unsigned short lds[TIH * TIW * CG * 8];

  const int bid = blockIdx.x;
  const int n = bid / (TY * TX);
  const int trem = bid % (TY * TX);
  const int ty0 = (trem / TX) * TH, tx0 = (trem % TX) * TW;

  // ---- stage input tile ----
  constexpr int ENT = TIH * TIW * CG;
  for (int e = threadIdx.x; e < ENT; e += 256) {
    int txx = e % TIW;
    int rr  = e / TIW;
    int cg  = rr % CG;
    int tyy = rr / CG;
    int iy, ix; bool ok;
    if (MODE == 0) {
      iy = ty0 + tyy - 1; ix = tx0 + txx - 1;
      ok = (unsigned)iy < (unsigned)HIN && (unsigned)ix < (unsigned)WIN;
    } else if (MODE == 1) {
      iy = 2 * ty0 + tyy - 1; ix = 2 * tx0 + txx - 1;
      ok = (unsigned)iy < (unsigned)HIN && (unsigned)ix < (unsigned)WIN;
    } else {
      int vy = ty0 + tyy - 1, vx = tx0 + txx - 1;
      ok = vy >= 0 && vx >= 0 && !(vy & 1) && !(vx & 1);
      iy = vy >> 1; ix = vx >> 1;
      ok = ok && iy < HIN && ix < WIN;
    }
    int4 val = {0, 0, 0, 0};
    if (ok) val = *(const int4*)&in[(((size_t)n * HIN + iy) * WIN + ix) * CIN + cg * 8];
    *(int4*)&lds[(size_t)e * 8] = val;
  }
  __syncthreads();

  const int lane = threadIdx.x & 63, wv = threadIdx.x >> 6;
  const int l15 = lane & 15, l4 = lane >> 4;

  f4_t acc[MPW][NT] = {};
  for (int ks = 0; ks < KS; ++ks) {
    const int tap = (ks * 32) / CIN;
    const int kh = tap / 3, kw = tap % 3;
    const int cb = ((ks * 32) % CIN) / 8 + l4;
    bf8_t bf[NT];
#pragma unroll
    for (int nt = 0; nt < NT; ++nt)
      bf[nt] = *(const bf8_t*)&wb[(size_t)(nt * 16 + l15) * K + ks * 32 + 8 * l4];
#pragma unroll
    for (int mi = 0; mi < MPW; ++mi) {
      int m = (wv * MPW + mi) * 16 + l15;
      int oy = m / TW, ox = m % TW;
      int rt = ((MODE == 1) ? 2 * oy : oy) + kh;
      int ct = ((MODE == 1) ? 2 * ox : ox) + kw;
      bf8_t a = *(const bf8_t*)&lds[(((size_t)rt * CG + cb) * TIW + ct) * 8];
#pragma unroll
      for (int nt = 0; nt < NT; ++nt)
        acc[mi][nt] = __builtin_amdgcn_mfma_f32_16x16x32_bf16(a, bf[nt], acc[mi][nt], 0, 0, 0);
    }
  }

  // ---- epilogue: bias + gelu + bf16 NHWC store ----
#pragma unroll
  for (int mi = 0; mi < MPW; ++mi) {
    int mbase = (wv * MPW + mi) * 16;
#pragma unroll
    for (int nt = 0; nt < NT; ++nt) {
      int co = nt * 16 + l15;
      float bv = bias[co];
#pragma unroll
      for (int r = 0; r < 4; ++r) {
        int m = mbase + l4 * 4 + r;
        int oy = m / TW, ox = m % TW;
        float v = acc[mi][nt][r] + bv;
        out[(((size_t)n * HO + ty0 + oy) * WO + (tx0 + ox)) * COUT + co] = f2bf(gelu_f(v));
      }
    }
  }
}

// ---------------------------------------------------------------------------
// MFMA GEMM: C[m][n] = act(sum_k A[m][k]*B[n][k] + bias). A,B bf16 [.][K].
// grid (N/64, M/64), 256 thr. BIASMODE 1 = dl permuted bias index.
// ---------------------------------------------------------------------------
template<int BIASMODE, bool GELU, bool OUTBF16>
__global__ __launch_bounds__(256) void gemm16_k(
    const unsigned short* __restrict__ A, const unsigned short* __restrict__ Bw,
    const float* __restrict__ bias, void* __restrict__ Cv, int M, int N, int K)
{
  const int lane = threadIdx.x & 63, wv = threadIdx.x >> 6;
  const int l15 = lane & 15, l4 = lane >> 4;
  const int mbase = blockIdx.y * 64 + wv * 16;
  const int nbase = blockIdx.x * 64;
  f4_t acc[4] = {};
  for (int k0 = 0; k0 < K; k0 += 32) {
    bf8_t a = *(const bf8_t*)&A[(size_t)(mbase + l15) * K + k0 + 8 * l4];
#pragma unroll
    for (int nt = 0; nt < 4; ++nt) {
      bf8_t b = *(const bf8_t*)&Bw[(size_t)(nbase + nt * 16 + l15) * K + k0 + 8 * l4];
      acc[nt] = __builtin_amdgcn_mfma_f32_16x16x32_bf16(a, b, acc[nt], 0, 0, 0);
    }
  }
#pragma unroll
  for (int nt = 0; nt < 4; ++nt) {
    int col = nbase + nt * 16 + l15;
    int bi = BIASMODE ? ((col & 63) * 64 + (col >> 6)) : col;
    float bv = bias[bi];
#pragma unroll
    for (int r = 0; r < 4; ++r) {
      int row = mbase + l4 * 4 + r;
      float v = acc[nt][r] + bv;
      if (GELU) v = gelu_f(v);
      if (OUTBF16) ((unsigned short*)Cv)[(size_t)row * N + col] = f2bf(v);
      else         ((float*)Cv)[(size_t)row * N + col] = v;
    }
  }
}

// ---------------------------------------------------------------------------
// dt3 (tconv 32->1, 32x32 -> 64x64) + tanh + fused loss partials. bf16 NHWC in.
// ---------------------------------------------------------------------------
__global__ __launch_bounds__(256) void dt3_loss_k(
    const unsigned short* __restrict__ in,  // (512,32,32,32) NHWC chunk
    const float* __restrict__ w,            // (32,1,3,3)
    const float* __restrict__ bias,
    const float* __restrict__ xref, const float* __restrict__ tref,
    float* __restrict__ fout, float* __restrict__ partials, int base)
{
  __shared__ float sw[288];
  for (int i = threadIdx.x; i < 288; i += 256) sw[i] = w[i];
  __syncthreads();
  int idx = blockIdx.x * 256 + threadIdx.x;
  int q = idx & 63, p = (idx >> 6) & 63, nl = idx >> 12;
  int n = base + nl;
  float acc = bias[0];
#pragma unroll
  for (int kh = 0; kh < 3; ++kh) {
    int u = p + kh - 1;
    if (u < 0 || (u & 1) || u >= 64) continue;
#pragma unroll
    for (int kw = 0; kw < 3; ++kw) {
      int v = q + kw - 1;
      if (v < 0 || (v & 1) || v >= 64) continue;
      const unsigned short* row = in + (((size_t)nl * 32 + (u >> 1)) * 32 + (v >> 1)) * 32;
      int wo = (2 - kh) * 3 + (2 - kw);
#pragma unroll
      for (int w2 = 0; w2 < 16; ++w2) {
        unsigned dv = *(const unsigned*)&row[w2 * 2];
        acc = fmaf(__uint_as_float(dv << 16),        sw[(2 * w2) * 9 + wo], acc);
        acc = fmaf(__uint_as_float(dv & 0xffff0000u), sw[(2 * w2 + 1) * 9 + wo], acc);
      }
    }
  }
  float val = tanhf(acc);
  float d;
  int pix = p * 64 + q;
  if (n < 512) {
    fout[(size_t)n * 4096 + pix] = val;
    d = val - tref[(size_t)n * 4096 + pix];
  } else {
    d = val - xref[(size_t)(n - 512) * 4096 + pix];
  }
  __shared__ float red[256];
  red[threadIdx.x] = d * d;
  __syncthreads();
#pragma unroll
  for (int s = 128; s > 0; s >>= 1) {
    if (threadIdx.x < s) red[threadIdx.x] += red[threadIdx.x + s];
    __syncthreads();
  }
  if (threadIdx.x == 0) partials[blockIdx.x] = red[0];
}

__global__ __launch_bounds__(256) void loss_final_k(
    const float* __restrict__ partials, float* __restrict__ out01)
{
  __shared__ float red[256];
  int base = blockIdx.x * 8192;
  float s = 0.f;
  for (int i = threadIdx.x; i < 8192; i += 256) s += partials[base + i];
  red[threadIdx.x] = s;
  __syncthreads();
#pragma unroll
  for (int st = 128; st > 0; st >>= 1) {
    if (threadIdx.x < st) red[threadIdx.x] += red[threadIdx.x + st];
    __syncthreads();
  }
  if (threadIdx.x == 0) out01[blockIdx.x] = red[0] * (1.0f / 2097152.0f);
}

// ---------------------------------------------------------------------------
// LSTM: 256 blocks x 128 threads. Block = output column j. All weights for
// that column LDS-resident (80 KB fp32). x/h rows staged per cell in LDS.
// ---------------------------------------------------------------------------
#define LSTM_NB 256

DEV void gridbar(unsigned* bar, unsigned target) {
  __syncthreads();
  if (threadIdx.x == 0) {
    __hip_atomic_fetch_add(bar, 1u, __ATOMIC_RELEASE, __HIP_MEMORY_SCOPE_AGENT);
    unsigned spins = 0;
    while (__hip_atomic_load(bar, __ATOMIC_RELAXED, __HIP_MEMORY_SCOPE_AGENT) < target) {
      __builtin_amdgcn_s_sleep(8);
      if (++spins > (1u << 22)) break;   // safety valve
    }
    (void)__hip_atomic_load(bar, __ATOMIC_ACQUIRE, __HIP_MEMORY_SCOPE_AGENT);
  }
  __syncthreads();
}

__global__ __launch_bounds__(128, 1) void lstm2_k(
    const float* __restrict__ z, const float* __restrict__ Wih,
    const float* __restrict__ Whh, const float* __restrict__ bih,
    const float* __restrict__ bhh, const float* __restrict__ lw,
    const float* __restrict__ lb,
    float* __restrict__ h, float* __restrict__ c, float* __restrict__ outs,
    unsigned* __restrict__ bar)
{
  __shared__ float swi[10 * 4 * 256];   // 40 KB
  __shared__ float swh[10 * 4 * 256];   // 40 KB
  __shared__ float sx[32 * 256];        // 32 KB
  __shared__ float sh[32 * 256];        // 32 KB
  __shared__ float sbias[40];
  __shared__ float slw[256];
  __shared__ float szg[4][32];

  const int j = blockIdx.x, tid = threadIdx.x;
  const int g = tid >> 5, b = tid & 31;

  for (int i4 = tid; i4 < 2560; i4 += 128) {     // 10240 floats / 4
    int l = i4 >> 8;                              // 256 float4 per layer
    int r = i4 & 255;
    int gg = r >> 6, k4 = r & 63;
    ((float4*)swi)[i4] = *(const float4*)&Wih[((size_t)l * 1024 + gg * 256 + j) * 256 + k4 * 4];
    ((float4*)swh)[i4] = *(const float4*)&Whh[((size_t)l * 1024 + gg * 256 + j) * 256 + k4 * 4];
  }
  if (tid < 40) {
    int l = tid >> 2, gg = tid & 3;
    sbias[tid] = bih[l * 1024 + gg * 256 + j] + bhh[l * 1024 + gg * 256 + j];
  }
  if (tid < 64) ((float4*)slw)[tid] = *(const float4*)&lw[(size_t)j * 256 + tid * 4];

  for (size_t i = (size_t)j * 128 + tid; i < 2u * 10 * 32 * 256; i += LSTM_NB * 128) h[i] = 0.f;
  for (size_t i = (size_t)j * 128 + tid; i < 10u * 32 * 256;     i += LSTM_NB * 128) c[i] = 0.f;

  unsigned ep = 0;
  ++ep; gridbar(bar, ep * LSTM_NB);

  for (int t = 0; t < 31; ++t) {
    const int cur = t & 1, prv = cur ^ 1;
    for (int l = 0; l < 10; ++l) {
      // stage x rows + h rows (32 x 256 each)
      for (int i4 = tid; i4 < 2048; i4 += 128) {
        int bb = i4 >> 6, k4 = i4 & 63;
        const float* xr;
        if (l == 0) xr = (t < 16) ? &z[(size_t)(bb * 32 + t) * 256]
                                  : &outs[(size_t)((t - 1) * 32 + bb) * 256];
        else        xr = &h[(size_t)((cur * 10 + l - 1) * 32 + bb) * 256];
        ((float4*)sx)[i4] = *(const float4*)&xr[k4 * 4];
        ((float4*)sh)[i4] = *(const float4*)&h[(size_t)((prv * 10 + l) * 32 + bb) * 256 + k4 * 4];
      }
      __syncthreads();
      const float4* xv = (const float4*)&sx[b * 256];
      const float4* hv = (const float4*)&sh[b * 256];
      const float4* wi = (const float4*)&swi[(l * 4 + g) * 256];
      const float4* wh = (const float4*)&swh[(l * 4 + g) * 256];
      float a0 = 0.f, a1 = 0.f, a2 = 0.f, a3 = 0.f;
#pragma unroll 8
      for (int k4 = 0; k4 < 64; ++k4) {
        float4 xa = xv[k4], wa = wi[k4];
        a0 = fmaf(xa.x, wa.x, a0); a1 = fmaf(xa.y, wa.y, a1);
        a2 = fmaf(xa.z, wa.z, a2); a3 = fmaf(xa.w, wa.w, a3);
        float4 hb = hv[k4], wb = wh[k4];
        a0 = fmaf(hb.x, wb.x, a0); a1 = fmaf(hb.y, wb.y, a1);
        a2 = fmaf(hb.z, wb.z, a2); a3 = fmaf(hb.w, wb.w, a3);
      }
      szg[g][b] = sbias[l * 4 + g] + ((a0 + a1) + (a2 + a3));
      __syncthreads();
      if (g == 0) {
        float zi = szg[0][b], zf = szg[1][b], zgg = szg[2][b], zo = szg[3][b];
        size_t ci_ = (size_t)(l * 32 + b) * 256 + j;
        float cold = c[ci_];
        float cn = sigm_f(zf) * cold + sigm_f(zi) * tanhf(zgg);
        c[ci_] = cn;
        h[(size_t)((cur * 10 + l) * 32 + b) * 256 + j] = sigm_f(zo) * tanhf(cn);
      }
      ++ep; gridbar(bar, ep * LSTM_NB);
    }
    if (t >= 15) {
      if (g == 0) {
        const float4* h9 = (const float4*)&h[(size_t)((cur * 10 + 9) * 32 + b) * 256];
        const float4* wl = (const float4*)slw;
        float a0 = 0.f, a1 = 0.f, a2 = 0.f, a3 = 0.f;
#pragma unroll 8
        for (int k4 = 0; k4 < 64; ++k4) {
          float4 xa = h9[k4], wa = wl[k4];
          a0 = fmaf(xa.x, wa.x, a0); a1 = fmaf(xa.y, wa.y, a1);
          a2 = fmaf(xa.z, wa.z, a2); a3 = fmaf(xa.w, wa.w, a3);
        }
        outs[(size_t)(t * 32 + b) * 256 + j] = lb[j] + ((a0 + a1) + (a2 + a3));
      }
      ++ep; gridbar(bar, ep * LSTM_NB);
    }
  }
}

// ---------------------------------------------------------------------------
// Decoder input gather -> bf16: rows 0..511 = y_t, rows 512..1023 = z_x
// ---------------------------------------------------------------------------
__global__ __launch_bounds__(256) void gather_dec_k(
    const float* __restrict__ outs, const float* __restrict__ z,
    unsigned short* __restrict__ ydec)
{
  int idx = blockIdx.x * 256 + threadIdx.x;   // < 262144
  int rrow = idx >> 8, k = idx & 255;
  float v;
  if (rrow < 512) {
    int b = rrow >> 4, i = rrow & 15;
    v = outs[(size_t)((15 + i) * 32 + b) * 256 + k];
  } else {
    int rr = rrow - 512;
    int b = rr >> 4, tt = rr & 15;
    v = z[(size_t)(b * 32 + tt) * 256 + k];
  }
  ydec[idx] = f2bf(v);
}

// ---------------------------------------------------------------------------
extern "C" void kernel_launch(void* const* d_in, const int* in_sizes, int n_in,
                              void* d_out, int out_size, void* d_ws, size_t ws_size,
                              hipStream_t stream) {
  const float* x     = (const float*)d_in[0];
  const float* t     = (const float*)d_in[1];
  const float* ec1_w = (const float*)d_in[2];
  const float* ec1_b = (const float*)d_in[3];
  const float* ec2_w = (const float*)d_in[4];
  const float* ec2_b = (const float*)d_in[5];
  const float* ec3_w = (const float*)d_in[6];
  const float* ec3_b = (const float*)d_in[7];
  const float* ec4_w = (const float*)d_in[8];
  const float* ec4_b = (const float*)d_in[9];
  const float* ec5_w = (const float*)d_in[10];
  const float* ec5_b = (const float*)d_in[11];
  const float* el_w  = (const float*)d_in[12];
  const float* el_b  = (const float*)d_in[13];
  const float* dl_w  = (const float*)d_in[14];
  const float* dl_b  = (const float*)d_in[15];
  const float* dt1_w = (const float*)d_in[16];
  const float* dt1_b = (const float*)d_in[17];
  const float* dc1_w = (const float*)d_in[18];
  const float* dc1_b = (const float*)d_in[19];
  const float* dt2_w = (const float*)d_in[20];
  const float* dt2_b = (const float*)d_in[21];
  const float* dc2_w = (const float*)d_in[22];
  const float* dc2_b = (const float*)d_in[23];
  const float* dt3_w = (const float*)d_in[24];
  const float* dt3_b = (const float*)d_in[25];
  const float* Wih   = (const float*)d_in[26];
  const float* Whh   = (const float*)d_in[27];
  const float* bih   = (const float*)d_in[28];
  const float* bhh   = (const float*)d_in[29];
  const float* lw    = (const float*)d_in[30];
  const float* lb    = (const float*)d_in[31];
  float* out = (float*)d_out;

  char* base = (char*)d_ws;
  size_t off = 0;
  auto alloc = [&](size_t bytes) -> char* {
    char* p = base + off;
    off += (bytes + 255) & ~(size_t)255;
    return p;
  };
  typedef unsigned short us;
  unsigned* bar   = (unsigned*)alloc(256);
  float* zbuf     = (float*)alloc((size_t)1024 * 256 * 4);
  float* hbuf     = (float*)alloc((size_t)2 * 10 * 32 * 256 * 4);
  float* cbuf     = (float*)alloc((size_t)10 * 32 * 256 * 4);
  float* outsbuf  = (float*)alloc((size_t)31 * 32 * 256 * 4);
  us*    ydec     = (us*)alloc((size_t)1024 * 256 * 2);
  float* partials = (float*)alloc((size_t)16384 * 4);
  us* wb_ec2 = (us*)alloc((size_t)32 * 288 * 2);
  us* wb_ec3 = (us*)alloc((size_t)64 * 288 * 2);
  us* wb_ec4 = (us*)alloc((size_t)64 * 576 * 2);
  us* wb_ec5 = (us*)alloc((size_t)64 * 576 * 2);
  us* wb_dt1 = (us*)alloc((size_t)64 * 576 * 2);
  us* wb_dc1 = (us*)alloc((size_t)64 * 576 * 2);
  us* wb_dt2 = (us*)alloc((size_t)32 * 576 * 2);
  us* wb_dc2 = (us*)alloc((size_t)32 * 288 * 2);
  us* elWb   = (us*)alloc((size_t)256 * 4096 * 2);
  us* dlWb   = (us*)alloc((size_t)4096 * 256 * 2);
  us* enc5   = (us*)alloc((size_t)1024 * 4096 * 2);          // 8.4 MB
  us* bufA   = (us*)alloc((size_t)512 * 32 * 32 * 32 * 2);   // 33.5 MB
  us* bufB   = (us*)alloc((size_t)512 * 32 * 32 * 32 * 2);   // 33.5 MB
  (void)in_sizes; (void)n_in; (void)out_size; (void)ws_size;

  hipMemsetAsync(bar, 0, 16, stream);

  // ---- weight prep ----
  prepw_k<<<(32*32*9+255)/256, 256, 0, stream>>>(ec2_w, wb_ec2, 32, 32, 0);
  prepw_k<<<(64*32*9+255)/256, 256, 0, stream>>>(ec3_w, wb_ec3, 64, 32, 0);
  prepw_k<<<(64*64*9+255)/256, 256, 0, stream>>>(ec4_w, wb_ec4, 64, 64, 0);
  prepw_k<<<(64*64*9+255)/256, 256, 0, stream>>>(ec5_w, wb_ec5, 64, 64, 0);
  prepw_k<<<(64*64*9+255)/256, 256, 0, stream>>>(dt1_w, wb_dt1, 64, 64, 1);
  prepw_k<<<(64*64*9+255)/256, 256, 0, stream>>>(dc1_w, wb_dc1, 64, 64, 0);
  prepw_k<<<(32*64*9+255)/256, 256, 0, stream>>>(dt2_w, wb_dt2, 32, 64, 1);
  prepw_k<<<(32*32*9+255)/256, 256, 0, stream>>>(dc2_w, wb_dc2, 32, 32, 0);
  prep_el_k<<<4096, 256, 0, stream>>>(el_w, elWb);
  prep_dl_k<<<4096, 256, 0, stream>>>(dl_w, dlWb);

  // ---- encoder: 2 chunks of 512 images ----
  for (int ch = 0; ch < 2; ++ch) {
    ec1_k<<<2048, 256, 0, stream>>>(x, t, ec1_w, ec1_b, bufA, ch * 512);
    convmf_k<32, 32, 32, 32, 32, 32, 0><<<512, 256, 0, stream>>>(bufA, wb_ec2, ec2_b, bufB);
    convmf_k<32, 64, 32, 32, 16, 16, 1><<<512, 256, 0, stream>>>(bufB, wb_ec3, ec3_b, bufA);
    convmf_k<64, 64, 16, 16, 16, 16, 0><<<512, 256, 0, stream>>>(bufA, wb_ec4, ec4_b, bufB);
    convmf_k<64, 64, 16, 16, 8, 8, 1><<<512, 256, 0, stream>>>(bufB, wb_ec5, ec5_b,
                                                               enc5 + (size_t)ch * 512 * 4096);
  }
  gemm16_k<0, false, false><<<dim3(4, 16), 256, 0, stream>>>(enc5, elWb, el_b, zbuf, 1024, 256, 4096);

  // ---- LSTM ----
  lstm2_k<<<LSTM_NB, 128, 0, stream>>>(zbuf, Wih, Whh, bih, bhh, lw, lb,
                                       hbuf, cbuf, outsbuf, bar);

  // ---- decoder: 2 chunks of 512 rows (chunk0 = pred, chunk1 = rec) ----
  gather_dec_k<<<1024, 256, 0, stream>>>(outsbuf, zbuf, ydec);
  for (int ch = 0; ch < 2; ++ch) {
    gemm16_k<1, true, true><<<dim3(64, 8), 256, 0, stream>>>(
        ydec + (size_t)ch * 512 * 256, dlWb, dl_b, bufB, 512, 4096, 256);
    convmf_k<64, 64, 8, 8, 16, 16, 2><<<512, 256, 0, stream>>>(bufB, wb_dt1, dt1_b, bufA);
    convmf_k<64, 64, 16, 16, 16, 16, 0><<<512, 256, 0, stream>>>(bufA, wb_dc1, dc1_b, bufB);
    convmf_k<64, 32, 16, 16, 16, 32, 2><<<1024, 256, 0, stream>>>(bufB, wb_dt2, dt2_b, bufA);
    convmf_k<32, 32, 32, 32, 32, 32, 0><<<512, 256, 0, stream>>>(bufA, wb_dc2, dc2_b, bufB);
    dt3_loss_k<<<8192, 256, 0, stream>>>(bufB, dt3_w, dt3_b, x, t, out + 2,
                                         partials + ch * 8192, ch * 512);
  }
  loss_final_k<<<2, 256, 0, stream>>>(partials, out);
}

// Round 4
// 2741.650 us; speedup vs baseline: 12.1394x; 3.1616x over previous
//
#include <hip/hip_runtime.h>
#include <math.h>

#define DEV __device__ __forceinline__

typedef __attribute__((ext_vector_type(8))) short bf8_t;   // 8 x bf16 (4 VGPR)
typedef __attribute__((ext_vector_type(4))) float f4_t;    // MFMA acc

DEV float gelu_f(float v) { return 0.5f * v * (1.0f + erff(v * 0.70710678118654752f)); }
DEV float sigm_f(float v) { return 1.0f / (1.0f + expf(-v)); }
DEV unsigned short f2bf(float f) {            // RNE float->bf16
  unsigned u = __float_as_uint(f);
  u = (u + 0x7FFFu + ((u >> 16) & 1u)) >> 16;
  return (unsigned short)u;
}
DEV float bf2f(unsigned short u) { return __uint_as_float((unsigned)u << 16); }

// ---------------------------------------------------------------------------
// Weight prep: conv weights -> bf16 [co][kh][kw][ci]; FLIP=1 for tconv
// ---------------------------------------------------------------------------
__global__ __launch_bounds__(256) void prepw_k(
    const float* __restrict__ w, unsigned short* __restrict__ wb,
    int COUT, int CIN, int FLIP)
{
  int idx = blockIdx.x * 256 + threadIdx.x;
  int total = COUT * CIN * 9;
  if (idx >= total) return;
  int ci = idx % CIN;
  int r  = idx / CIN;
  int kw = r % 3; r /= 3;
  int kh = r % 3;
  int co = r / 3;
  float v = FLIP ? w[((ci * COUT + co) * 3 + (2 - kh)) * 3 + (2 - kw)]
                 : w[((co * CIN + ci) * 3 + kh) * 3 + kw];
  wb[idx] = f2bf(v);
}

// el_w (256,4096 k_ref=c*64+s) -> bf16 [n][k_new=(s*64+c)]
__global__ __launch_bounds__(256) void prep_el_k(
    const float* __restrict__ w, unsigned short* __restrict__ wb)
{
  int idx = blockIdx.x * 256 + threadIdx.x;     // < 256*4096
  int kn = idx & 4095, n = idx >> 12;
  wb[idx] = f2bf(w[(size_t)n * 4096 + ((kn & 63) * 64 + (kn >> 6))]);
}

// dl_w (4096,256) row r=c*64+s -> bf16 rows nout=s*64+c
__global__ __launch_bounds__(256) void prep_dl_k(
    const float* __restrict__ w, unsigned short* __restrict__ wb)
{
  int idx = blockIdx.x * 256 + threadIdx.x;     // < 4096*256
  int k = idx & 255, nout = idx >> 8;
  wb[idx] = f2bf(w[(size_t)((nout & 63) * 64 + (nout >> 6)) * 256 + k]);
}

// LSTM weights (10,1024,256) -> bf16 frag-contiguous:
// wb[((l*64+nt)*8+ks)*512 + lane*8 + e] = W[l][nt*16+(lane&15)][ks*32+(lane>>4)*8+e]
__global__ __launch_bounds__(256) void prep_wlstm_k(
    const float* __restrict__ w, unsigned short* __restrict__ wb)
{
  int idx = blockIdx.x * 256 + threadIdx.x;   // exactly 2621440 = 10240 blocks
  int e = idx & 7, lane = (idx >> 3) & 63, ks = (idx >> 9) & 7;
  int nt = (idx >> 12) & 63, l = idx >> 18;
  wb[idx] = f2bf(w[((size_t)l * 1024 + nt * 16 + (lane & 15)) * 256
                   + ks * 32 + (lane >> 4) * 8 + e]);
}

// lw (256,256) -> bf16 frag-contiguous (nt<16)
__global__ __launch_bounds__(256) void prep_lwswz_k(
    const float* __restrict__ w, unsigned short* __restrict__ wb)
{
  int idx = blockIdx.x * 256 + threadIdx.x;   // exactly 65536 = 256 blocks
  int e = idx & 7, lane = (idx >> 3) & 63, ks = (idx >> 9) & 7, nt = idx >> 12;
  wb[idx] = f2bf(w[(size_t)(nt * 16 + (lane & 15)) * 256
                   + ks * 32 + (lane >> 4) * 8 + e]);
}

// ---------------------------------------------------------------------------
// ec1: 1ch 64x64 s2 -> 32ch 32x32, NHWC bf16 out. base=chunk img offset.
// ---------------------------------------------------------------------------
__global__ __launch_bounds__(256) void ec1_k(
    const float* __restrict__ x, const float* __restrict__ t,
    const float* __restrict__ w, const float* __restrict__ bias,
    unsigned short* __restrict__ out, int base)
{
  __shared__ float sw[288];
  __shared__ float sb[32];
  for (int i = threadIdx.x; i < 288; i += 256) sw[i] = w[i];
  if (threadIdx.x < 32) sb[threadIdx.x] = bias[threadIdx.x];
  __syncthreads();
  int idx = blockIdx.x * 256 + threadIdx.x;     // < 512*32*32
  int ox = idx & 31, oy = (idx >> 5) & 31, nl = idx >> 10;
  int n = base + nl;
  int b = n >> 5, j = n & 31;
  const float* ip = (j < 16) ? (x + (size_t)(b * 16 + j) * 4096)
                             : (t + (size_t)(b * 16 + j - 16) * 4096);
  float pv[9];
#pragma unroll
  for (int kh = 0; kh < 3; ++kh) {
    int iy = oy * 2 + kh - 1;
#pragma unroll
    for (int kw = 0; kw < 3; ++kw) {
      int ix = ox * 2 + kw - 1;
      pv[kh * 3 + kw] = ((unsigned)iy < 64u && (unsigned)ix < 64u) ? ip[iy * 64 + ix] : 0.f;
    }
  }
  unsigned short u[32];
#pragma unroll
  for (int co = 0; co < 32; ++co) {
    float a = sb[co];
#pragma unroll
    for (int i = 0; i < 9; ++i) a = fmaf(pv[i], sw[co * 9 + i], a);
    u[co] = f2bf(gelu_f(a));
  }
  unsigned short* op = out + (size_t)idx * 32;
#pragma unroll
  for (int p = 0; p < 4; ++p) {
    uint4 v;
    v.x = u[p*8+0] | (u[p*8+1] << 16);
    v.y = u[p*8+2] | (u[p*8+3] << 16);
    v.z = u[p*8+4] | (u[p*8+5] << 16);
    v.w = u[p*8+6] | (u[p*8+7] << 16);
    *(uint4*)&op[p * 8] = v;
  }
}

// ---------------------------------------------------------------------------
// MFMA implicit-GEMM conv. NHWC bf16 in/out. MODE: 0=s1, 1=s2, 2=tconv(ups2).
// ---------------------------------------------------------------------------
template<int CIN, int COUT, int HIN, int WIN, int TH, int TW, int MODE>
__global__ __launch_bounds__(256) void convmf_k(
    const unsigned short* __restrict__ in, const unsigned short* __restrict__ wb,
    const float* __restrict__ bias, unsigned short* __restrict__ out)
{
  constexpr int HO  = (MODE == 1) ? HIN / 2 : (MODE == 2 ? HIN * 2 : HIN);
  constexpr int WO  = (MODE == 1) ? WIN / 2 : (MODE == 2 ? WIN * 2 : WIN);
  constexpr int TIH = (MODE == 1) ? 2 * TH + 1 : TH + 2;
  constexpr int TIW = (MODE == 1) ? 2 * TW + 1 : TW + 2;
  constexpr int CG  = CIN / 8;
  constexpr int K   = 9 * CIN;
  constexpr int KS  = K / 32;
  constexpr int NT  = COUT / 16;
  constexpr int MT  = (TH * TW) / 16;
  constexpr int MPW = MT / 4;
  constexpr int TY  = HO / TH, TX = WO / TW;

  __shared__ unsigned short lds[TIH * TIW * CG * 8];

  const int bid = blockIdx.x;
  const int n = bid / (TY * TX);
  const int trem = bid % (TY * TX);
  const int ty0 = (trem / TX) * TH, tx0 = (trem % TX) * TW;

  constexpr int ENT = TIH * TIW * CG;
  for (int e = threadIdx.x; e < ENT; e += 256) {
    int txx = e % TIW;
    int rr  = e / TIW;
    int cg  = rr % CG;
    int tyy = rr / CG;
    int iy, ix; bool ok;
    if (MODE == 0) {
      iy = ty0 + tyy - 1; ix = tx0 + txx - 1;
      ok = (unsigned)iy < (unsigned)HIN && (unsigned)ix < (unsigned)WIN;
    } else if (MODE == 1) {
      iy = 2 * ty0 + tyy - 1; ix = 2 * tx0 + txx - 1;
      ok = (unsigned)iy < (unsigned)HIN && (unsigned)ix < (unsigned)WIN;
    } else {
      int vy = ty0 + tyy - 1, vx = tx0 + txx - 1;
      ok = vy >= 0 && vx >= 0 && !(vy & 1) && !(vx & 1);
      iy = vy >> 1; ix = vx >> 1;
      ok = ok && iy < HIN && ix < WIN;
    }
    int4 val = {0, 0, 0, 0};
    if (ok) val = *(const int4*)&in[(((size_t)n * HIN + iy) * WIN + ix) * CIN + cg * 8];
    *(int4*)&lds[(size_t)e * 8] = val;
  }
  __syncthreads();

  const int lane = threadIdx.x & 63, wv = threadIdx.x >> 6;
  const int l15 = lane & 15, l4 = lane >> 4;

  f4_t acc[MPW][NT] = {};
  for (int ks = 0; ks < KS; ++ks) {
    const int tap = (ks * 32) / CIN;
    const int kh = tap / 3, kw = tap % 3;
    const int cb = ((ks * 32) % CIN) / 8 + l4;
    bf8_t bf[NT];
#pragma unroll
    for (int nt = 0; nt < NT; ++nt)
      bf[nt] = *(const bf8_t*)&wb[(size_t)(nt * 16 + l15) * K + ks * 32 + 8 * l4];
#pragma unroll
    for (int mi = 0; mi < MPW; ++mi) {
      int m = (wv * MPW + mi) * 16 + l15;
      int oy = m / TW, ox = m % TW;
      int rt = ((MODE == 1) ? 2 * oy : oy) + kh;
      int ct = ((MODE == 1) ? 2 * ox : ox) + kw;
      bf8_t a = *(const bf8_t*)&lds[(((size_t)rt * CG + cb) * TIW + ct) * 8];
#pragma unroll
      for (int nt = 0; nt < NT; ++nt)
        acc[mi][nt] = __builtin_amdgcn_mfma_f32_16x16x32_bf16(a, bf[nt], acc[mi][nt], 0, 0, 0);
    }
  }

#pragma unroll
  for (int mi = 0; mi < MPW; ++mi) {
    int mbase = (wv * MPW + mi) * 16;
#pragma unroll
    for (int nt = 0; nt < NT; ++nt) {
      int co = nt * 16 + l15;
      float bv = bias[co];
#pragma unroll
      for (int r = 0; r < 4; ++r) {
        int m = mbase + l4 * 4 + r;
        int oy = m / TW, ox = m % TW;
        float v = acc[mi][nt][r] + bv;
        out[(((size_t)n * HO + ty0 + oy) * WO + (tx0 + ox)) * COUT + co] = f2bf(gelu_f(v));
      }
    }
  }
}

// ---------------------------------------------------------------------------
// MFMA GEMM: C[m][n] = act(sum_k A[m][k]*B[n][k] + bias).
// ---------------------------------------------------------------------------
template<int BIASMODE, bool GELU, bool OUTBF16>
__global__ __launch_bounds__(256) void gemm16_k(
    const unsigned short* __restrict__ A, const unsigned short* __restrict__ Bw,
    const float* __restrict__ bias, void* __restrict__ Cv, int M, int N, int K)
{
  const int lane = threadIdx.x & 63, wv = threadIdx.x >> 6;
  const int l15 = lane & 15, l4 = lane >> 4;
  const int mbase = blockIdx.y * 64 + wv * 16;
  const int nbase = blockIdx.x * 64;
  f4_t acc[4] = {};
  for (int k0 = 0; k0 < K; k0 += 32) {
    bf8_t a = *(const bf8_t*)&A[(size_t)(mbase + l15) * K + k0 + 8 * l4];
#pragma unroll
    for (int nt = 0; nt < 4; ++nt) {
      bf8_t b = *(const bf8_t*)&Bw[(size_t)(nbase + nt * 16 + l15) * K + k0 + 8 * l4];
      acc[nt] = __builtin_amdgcn_mfma_f32_16x16x32_bf16(a, b, acc[nt], 0, 0, 0);
    }
  }
#pragma unroll
  for (int nt = 0; nt < 4; ++nt) {
    int col = nbase + nt * 16 + l15;
    int bi = BIASMODE ? ((col & 63) * 64 + (col >> 6)) : col;
    float bv = bias[bi];
#pragma unroll
    for (int r = 0; r < 4; ++r) {
      int row = mbase + l4 * 4 + r;
      float v = acc[nt][r] + bv;
      if (GELU) v = gelu_f(v);
      if (OUTBF16) ((unsigned short*)Cv)[(size_t)row * N + col] = f2bf(v);
      else         ((float*)Cv)[(size_t)row * N + col] = v;
    }
  }
}

// ---------------------------------------------------------------------------
// dt3 (tconv 32->1) + tanh + fused loss partials. bf16 NHWC in.
// ---------------------------------------------------------------------------
__global__ __launch_bounds__(256) void dt3_loss_k(
    const unsigned short* __restrict__ in,
    const float* __restrict__ w, const float* __restrict__ bias,
    const float* __restrict__ xref, const float* __restrict__ tref,
    float* __restrict__ fout, float* __restrict__ partials, int base)
{
  __shared__ float sw[288];
  for (int i = threadIdx.x; i < 288; i += 256) sw[i] = w[i];
  __syncthreads();
  int idx = blockIdx.x * 256 + threadIdx.x;
  int q = idx & 63, p = (idx >> 6) & 63, nl = idx >> 12;
  int n = base + nl;
  float acc = bias[0];
#pragma unroll
  for (int kh = 0; kh < 3; ++kh) {
    int u = p + kh - 1;
    if (u < 0 || (u & 1) || u >= 64) continue;
#pragma unroll
    for (int kw = 0; kw < 3; ++kw) {
      int v = q + kw - 1;
      if (v < 0 || (v & 1) || v >= 64) continue;
      const unsigned short* row = in + (((size_t)nl * 32 + (u >> 1)) * 32 + (v >> 1)) * 32;
      int wo = (2 - kh) * 3 + (2 - kw);
#pragma unroll
      for (int w2 = 0; w2 < 16; ++w2) {
        unsigned dv = *(const unsigned*)&row[w2 * 2];
        acc = fmaf(__uint_as_float(dv << 16),        sw[(2 * w2) * 9 + wo], acc);
        acc = fmaf(__uint_as_float(dv & 0xffff0000u), sw[(2 * w2 + 1) * 9 + wo], acc);
      }
    }
  }
  float val = tanhf(acc);
  float d;
  int pix = p * 64 + q;
  if (n < 512) {
    fout[(size_t)n * 4096 + pix] = val;
    d = val - tref[(size_t)n * 4096 + pix];
  } else {
    d = val - xref[(size_t)(n - 512) * 4096 + pix];
  }
  __shared__ float red[256];
  red[threadIdx.x] = d * d;
  __syncthreads();
#pragma unroll
  for (int s = 128; s > 0; s >>= 1) {
    if (threadIdx.x < s) red[threadIdx.x] += red[threadIdx.x + s];
    __syncthreads();
  }
  if (threadIdx.x == 0) partials[blockIdx.x] = red[0];
}

__global__ __launch_bounds__(256) void loss_final_k(
    const float* __restrict__ partials, float* __restrict__ out01)
{
  __shared__ float red[256];
  int base = blockIdx.x * 8192;
  float s = 0.f;
  for (int i = threadIdx.x; i < 8192; i += 256) s += partials[base + i];
  red[threadIdx.x] = s;
  __syncthreads();
#pragma unroll
  for (int st = 128; st > 0; st >>= 1) {
    if (threadIdx.x < st) red[threadIdx.x] += red[threadIdx.x + st];
    __syncthreads();
  }
  if (threadIdx.x == 0) out01[blockIdx.x] = red[0] * (1.0f / 2097152.0f);
}

// ---------------------------------------------------------------------------
// LSTM v3: MFMA-based. 32 blocks x 256 thr (4 waves). Block=(mt,jg):
//   mt = batch m-tile (16 rows), jg = 16-col group. Wave wv = gate.
// Per cell: each wave does 16x mfma_16x16x32_bf16 (x@Wih + h@Whh),
// z exchanged via LDS, c in block LDS, h via parity-dbuf global bf16.
// Grid barrier (agent-scope release/acquire) per cell, proven in r2/r3.
// ---------------------------------------------------------------------------
#define LSTM_NB 32

DEV void gridbar(unsigned* bar, unsigned target) {
  __syncthreads();
  if (threadIdx.x == 0) {
    __hip_atomic_fetch_add(bar, 1u, __ATOMIC_RELEASE, __HIP_MEMORY_SCOPE_AGENT);
    unsigned spins = 0;
    while (__hip_atomic_load(bar, __ATOMIC_RELAXED, __HIP_MEMORY_SCOPE_AGENT) < target) {
      __builtin_amdgcn_s_sleep(2);
      if (++spins > (1u << 24)) break;   // safety valve
    }
    (void)__hip_atomic_load(bar, __ATOMIC_ACQUIRE, __HIP_MEMORY_SCOPE_AGENT);
  }
  __syncthreads();
}

__global__ __launch_bounds__(256, 1) void lstm3_k(
    const float* __restrict__ z,          // (1024,256) fp32, row = b*32+t
    const unsigned short* __restrict__ wihb,  // frag-swizzled bf16
    const unsigned short* __restrict__ whhb,
    const float* __restrict__ bih, const float* __restrict__ bhh,
    const unsigned short* __restrict__ lwb,   // frag-swizzled bf16 (16 nt)
    const float* __restrict__ lb,
    unsigned short* __restrict__ zbf,     // (31? no: 16 used)(32,256) bf16 [t][b][k]
    unsigned short* __restrict__ hbf,     // (2,10,32,256) bf16
    unsigned short* __restrict__ outsbf,  // (32,256) bf16
    float* __restrict__ outs,             // (31,32,256) fp32
    unsigned* __restrict__ bar)
{
  __shared__ float zsm[4 * 272];      // [gate][b*17 + j], padded
  __shared__ float cls[10 * 256];     // c state, [l][tid]
  __shared__ float sbias[640];        // bih+bhh, [l][g][j]
  __shared__ float slb[16];

  const int tid = threadIdx.x;
  const int mt = blockIdx.x >> 4, jg = blockIdx.x & 15;
  const int m0 = mt * 16;
  const int lane = tid & 63, wv = tid >> 6;
  const int l15 = lane & 15, l4 = lane >> 4;
  const int gtid = blockIdx.x * 256 + tid;

  // ---- init: zbf transpose+bf16, zero hbf parity-1, zero c, stage biases ----
  for (int i = gtid; i < 16 * 32 * 256; i += LSTM_NB * 256) {
    int k = i & 255, r = i >> 8;              // dest row r = t*32 + b
    int tt = r >> 5, b = r & 31;
    zbf[i] = f2bf(z[(size_t)(b * 32 + tt) * 256 + k]);
  }
  for (int i = gtid; i < 81920; i += LSTM_NB * 256) hbf[81920 + i] = 0;
  for (int i = tid; i < 2560; i += 256) cls[i] = 0.f;
  for (int i = tid; i < 640; i += 256) {
    int l = i >> 6, g = (i >> 4) & 3, j = i & 15;
    sbias[i] = bih[l * 1024 + g * 256 + jg * 16 + j]
             + bhh[l * 1024 + g * 256 + jg * 16 + j];
  }
  if (tid < 16) slb[tid] = lb[jg * 16 + tid];

  unsigned ep = 0;
  ++ep; gridbar(bar, ep * LSTM_NB);

  for (int t = 0; t < 31; ++t) {
    const int cur = t & 1, prv = cur ^ 1;
    const unsigned short* xb0 = (t < 16) ? (zbf + (size_t)t * 32 * 256) : outsbf;
    for (int l = 0; l < 10; ++l) {
      const unsigned short* xb = (l == 0) ? xb0
                                 : (hbf + (size_t)((cur * 10 + l - 1) * 32) * 256);
      const unsigned short* hb = hbf + (size_t)((prv * 10 + l) * 32) * 256;
      const unsigned short* wi = wihb + (size_t)((l * 64 + wv * 16 + jg) * 8) * 512;
      const unsigned short* wh = whhb + (size_t)((l * 64 + wv * 16 + jg) * 8) * 512;
      f4_t a0 = {}, a1 = {};
#pragma unroll
      for (int ks = 0; ks < 8; ++ks) {
        bf8_t av = *(const bf8_t*)&xb[(m0 + l15) * 256 + ks * 32 + l4 * 8];
        bf8_t bv = *(const bf8_t*)&wi[ks * 512 + lane * 8];
        a0 = __builtin_amdgcn_mfma_f32_16x16x32_bf16(av, bv, a0, 0, 0, 0);
      }
#pragma unroll
      for (int ks = 0; ks < 8; ++ks) {
        bf8_t av = *(const bf8_t*)&hb[(m0 + l15) * 256 + ks * 32 + l4 * 8];
        bf8_t bv = *(const bf8_t*)&wh[ks * 512 + lane * 8];
        a1 = __builtin_amdgcn_mfma_f32_16x16x32_bf16(av, bv, a1, 0, 0, 0);
      }
#pragma unroll
      for (int r = 0; r < 4; ++r)
        zsm[wv * 272 + (l4 * 4 + r) * 17 + l15] = a0[r] + a1[r];
      __syncthreads();
      {
        int b = tid >> 4, j = tid & 15;
        float zi = zsm[0 * 272 + b * 17 + j] + sbias[l * 64 + j];
        float zf = zsm[1 * 272 + b * 17 + j] + sbias[l * 64 + 16 + j];
        float zg = zsm[2 * 272 + b * 17 + j] + sbias[l * 64 + 32 + j];
        float zo = zsm[3 * 272 + b * 17 + j] + sbias[l * 64 + 48 + j];
        float cold = cls[l * 256 + tid];
        float cn = sigm_f(zf) * cold + sigm_f(zi) * tanhf(zg);
        cls[l * 256 + tid] = cn;
        float hn = sigm_f(zo) * tanhf(cn);
        hbf[(size_t)((cur * 10 + l) * 32 + m0 + b) * 256 + jg * 16 + j] = f2bf(hn);
      }
      ++ep; gridbar(bar, ep * LSTM_NB);
    }
    if (t >= 15) {
      if (wv == 0) {
        const unsigned short* hb9 = hbf + (size_t)((cur * 10 + 9) * 32) * 256;
        f4_t acc = {};
#pragma unroll
        for (int ks = 0; ks < 8; ++ks) {
          bf8_t av = *(const bf8_t*)&hb9[(m0 + l15) * 256 + ks * 32 + l4 * 8];
          bf8_t bv = *(const bf8_t*)&lwb[(jg * 8 + ks) * 512 + lane * 8];
          acc = __builtin_amdgcn_mfma_f32_16x16x32_bf16(av, bv, acc, 0, 0, 0);
        }
#pragma unroll
        for (int r = 0; r < 4; ++r) {
          int b = m0 + l4 * 4 + r, n = jg * 16 + l15;
          float v = acc[r] + slb[l15];
          outs[(size_t)(t * 32 + b) * 256 + n] = v;
          outsbf[b * 256 + n] = f2bf(v);
        }
      }
      ++ep; gridbar(bar, ep * LSTM_NB);
    }
  }
}

// ---------------------------------------------------------------------------
// Decoder input gather -> bf16: rows 0..511 = y_t, rows 512..1023 = z_x
// ---------------------------------------------------------------------------
__global__ __launch_bounds__(256) void gather_dec_k(
    const float* __restrict__ outs, const float* __restrict__ z,
    unsigned short* __restrict__ ydec)
{
  int idx = blockIdx.x * 256 + threadIdx.x;   // < 262144
  int rrow = idx >> 8, k = idx & 255;
  float v;
  if (rrow < 512) {
    int b = rrow >> 4, i = rrow & 15;
    v = outs[(size_t)((15 + i) * 32 + b) * 256 + k];
  } else {
    int rr = rrow - 512;
    int b = rr >> 4, tt = rr & 15;
    v = z[(size_t)(b * 32 + tt) * 256 + k];
  }
  ydec[idx] = f2bf(v);
}

// ---------------------------------------------------------------------------
extern "C" void kernel_launch(void* const* d_in, const int* in_sizes, int n_in,
                              void* d_out, int out_size, void* d_ws, size_t ws_size,
                              hipStream_t stream) {
  const float* x     = (const float*)d_in[0];
  const float* t     = (const float*)d_in[1];
  const float* ec1_w = (const float*)d_in[2];
  const float* ec1_b = (const float*)d_in[3];
  const float* ec2_w = (const float*)d_in[4];
  const float* ec2_b = (const float*)d_in[5];
  const float* ec3_w = (const float*)d_in[6];
  const float* ec3_b = (const float*)d_in[7];
  const float* ec4_w = (const float*)d_in[8];
  const float* ec4_b = (const float*)d_in[9];
  const float* ec5_w = (const float*)d_in[10];
  const float* ec5_b = (const float*)d_in[11];
  const float* el_w  = (const float*)d_in[12];
  const float* el_b  = (const float*)d_in[13];
  const float* dl_w  = (const float*)d_in[14];
  const float* dl_b  = (const float*)d_in[15];
  const float* dt1_w = (const float*)d_in[16];
  const float* dt1_b = (const float*)d_in[17];
  const float* dc1_w = (const float*)d_in[18];
  const float* dc1_b = (const float*)d_in[19];
  const float* dt2_w = (const float*)d_in[20];
  const float* dt2_b = (const float*)d_in[21];
  const float* dc2_w = (const float*)d_in[22];
  const float* dc2_b = (const float*)d_in[23];
  const float* dt3_w = (const float*)d_in[24];
  const float* dt3_b = (const float*)d_in[25];
  const float* Wih   = (const float*)d_in[26];
  const float* Whh   = (const float*)d_in[27];
  const float* bih   = (const float*)d_in[28];
  const float* bhh   = (const float*)d_in[29];
  const float* lw    = (const float*)d_in[30];
  const float* lb    = (const float*)d_in[31];
  float* out = (float*)d_out;

  char* base = (char*)d_ws;
  size_t off = 0;
  auto alloc = [&](size_t bytes) -> char* {
    char* p = base + off;
    off += (bytes + 255) & ~(size_t)255;
    return p;
  };
  typedef unsigned short us;
  unsigned* bar   = (unsigned*)alloc(256);
  float* zbuf     = (float*)alloc((size_t)1024 * 256 * 4);
  float* outsbuf  = (float*)alloc((size_t)31 * 32 * 256 * 4);
  us*    zbf      = (us*)alloc((size_t)16 * 32 * 256 * 2);
  us*    hbf      = (us*)alloc((size_t)2 * 10 * 32 * 256 * 2);
  us*    outsbf   = (us*)alloc((size_t)32 * 256 * 2);
  us*    ydec     = (us*)alloc((size_t)1024 * 256 * 2);
  float* partials = (float*)alloc((size_t)16384 * 4);
  us* wb_ec2 = (us*)alloc((size_t)32 * 288 * 2);
  us* wb_ec3 = (us*)alloc((size_t)64 * 288 * 2);
  us* wb_ec4 = (us*)alloc((size_t)64 * 576 * 2);
  us* wb_ec5 = (us*)alloc((size_t)64 * 576 * 2);
  us* wb_dt1 = (us*)alloc((size_t)64 * 576 * 2);
  us* wb_dc1 = (us*)alloc((size_t)64 * 576 * 2);
  us* wb_dt2 = (us*)alloc((size_t)32 * 576 * 2);
  us* wb_dc2 = (us*)alloc((size_t)32 * 288 * 2);
  us* elWb   = (us*)alloc((size_t)256 * 4096 * 2);
  us* dlWb   = (us*)alloc((size_t)4096 * 256 * 2);
  us* wihb   = (us*)alloc((size_t)10 * 1024 * 256 * 2);      // 5 MB
  us* whhb   = (us*)alloc((size_t)10 * 1024 * 256 * 2);      // 5 MB
  us* lwb    = (us*)alloc((size_t)256 * 256 * 2);
  us* enc5   = (us*)alloc((size_t)1024 * 4096 * 2);          // 8.4 MB
  us* bufA   = (us*)alloc((size_t)512 * 32 * 32 * 32 * 2);   // 33.5 MB
  us* bufB   = (us*)alloc((size_t)512 * 32 * 32 * 32 * 2);   // 33.5 MB
  (void)in_sizes; (void)n_in; (void)out_size; (void)ws_size;

  hipMemsetAsync(bar, 0, 16, stream);

  // ---- weight prep ----
  prepw_k<<<(32*32*9+255)/256, 256, 0, stream>>>(ec2_w, wb_ec2, 32, 32, 0);
  prepw_k<<<(64*32*9+255)/256, 256, 0, stream>>>(ec3_w, wb_ec3, 64, 32, 0);
  prepw_k<<<(64*64*9+255)/256, 256, 0, stream>>>(ec4_w, wb_ec4, 64, 64, 0);
  prepw_k<<<(64*64*9+255)/256, 256, 0, stream>>>(ec5_w, wb_ec5, 64, 64, 0);
  prepw_k<<<(64*64*9+255)/256, 256, 0, stream>>>(dt1_w, wb_dt1, 64, 64, 1);
  prepw_k<<<(64*64*9+255)/256, 256, 0, stream>>>(dc1_w, wb_dc1, 64, 64, 0);
  prepw_k<<<(32*64*9+255)/256, 256, 0, stream>>>(dt2_w, wb_dt2, 32, 64, 1);
  prepw_k<<<(32*32*9+255)/256, 256, 0, stream>>>(dc2_w, wb_dc2, 32, 32, 0);
  prep_el_k<<<4096, 256, 0, stream>>>(el_w, elWb);
  prep_dl_k<<<4096, 256, 0, stream>>>(dl_w, dlWb);
  prep_wlstm_k<<<10240, 256, 0, stream>>>(Wih, wihb);
  prep_wlstm_k<<<10240, 256, 0, stream>>>(Whh, whhb);
  prep_lwswz_k<<<256, 256, 0, stream>>>(lw, lwb);

  // ---- encoder: 2 chunks of 512 images ----
  for (int ch = 0; ch < 2; ++ch) {
    ec1_k<<<2048, 256, 0, stream>>>(x, t, ec1_w, ec1_b, bufA, ch * 512);
    convmf_k<32, 32, 32, 32, 32, 32, 0><<<512, 256, 0, stream>>>(bufA, wb_ec2, ec2_b, bufB);
    convmf_k<32, 64, 32, 32, 16, 16, 1><<<512, 256, 0, stream>>>(bufB, wb_ec3, ec3_b, bufA);
    convmf_k<64, 64, 16, 16, 16, 16, 0><<<512, 256, 0, stream>>>(bufA, wb_ec4, ec4_b, bufB);
    convmf_k<64, 64, 16, 16, 8, 8, 1><<<512, 256, 0, stream>>>(bufB, wb_ec5, ec5_b,
                                                               enc5 + (size_t)ch * 512 * 4096);
  }
  gemm16_k<0, false, false><<<dim3(4, 16), 256, 0, stream>>>(enc5, elWb, el_b, zbuf, 1024, 256, 4096);

  // ---- LSTM (MFMA, 32 blocks, grid-barriered) ----
  lstm3_k<<<LSTM_NB, 256, 0, stream>>>(zbuf, wihb, whhb, bih, bhh, lwb, lb,
                                       zbf, hbf, outsbf, outsbuf, bar);

  // ---- decoder: 2 chunks of 512 rows (chunk0 = pred, chunk1 = rec) ----
  gather_dec_k<<<1024, 256, 0, stream>>>(outsbuf, zbuf, ydec);
  for (int ch = 0; ch < 2; ++ch) {
    gemm16_k<1, true, true><<<dim3(64, 8), 256, 0, stream>>>(
        ydec + (size_t)ch * 512 * 256, dlWb, dl_b, bufB, 512, 4096, 256);
    convmf_k<64, 64, 8, 8, 16, 16, 2><<<512, 256, 0, stream>>>(bufB, wb_dt1, dt1_b, bufA);
    convmf_k<64, 64, 16, 16, 16, 16, 0><<<512, 256, 0, stream>>>(bufA, wb_dc1, dc1_b, bufB);
    convmf_k<64, 32, 16, 16, 16, 32, 2><<<1024, 256, 0, stream>>>(bufB, wb_dt2, dt2_b, bufA);
    convmf_k<32, 32, 32, 32, 32, 32, 0><<<512, 256, 0, stream>>>(bufA, wb_dc2, dc2_b, bufB);
    dt3_loss_k<<<8192, 256, 0, stream>>>(bufB, dt3_w, dt3_b, x, t, out + 2,
                                         partials + ch * 8192, ch * 512);
  }
  loss_final_k<<<2, 256, 0, stream>>>(partials, out);
}

// Round 5
// 2724.934 us; speedup vs baseline: 12.2138x; 1.0061x over previous
//
#include <hip/hip_runtime.h>
#include <math.h>

#define DEV __device__ __forceinline__

typedef __attribute__((ext_vector_type(8))) short bf8_t;   // 8 x bf16 (4 VGPR)
typedef __attribute__((ext_vector_type(4))) float f4_t;    // MFMA acc

DEV float gelu_f(float v) { return 0.5f * v * (1.0f + erff(v * 0.70710678118654752f)); }
DEV float sigm_f(float v) { return 1.0f / (1.0f + expf(-v)); }
DEV unsigned short f2bf(float f) {            // RNE float->bf16
  unsigned u = __float_as_uint(f);
  u = (u + 0x7FFFu + ((u >> 16) & 1u)) >> 16;
  return (unsigned short)u;
}
DEV float bf2f(unsigned short u) { return __uint_as_float((unsigned)u << 16); }

// ---------------------------------------------------------------------------
// Weight prep: conv weights -> bf16 [co][kh][kw][ci]; FLIP=1 for tconv
// ---------------------------------------------------------------------------
__global__ __launch_bounds__(256) void prepw_k(
    const float* __restrict__ w, unsigned short* __restrict__ wb,
    int COUT, int CIN, int FLIP)
{
  int idx = blockIdx.x * 256 + threadIdx.x;
  int total = COUT * CIN * 9;
  if (idx >= total) return;
  int ci = idx % CIN;
  int r  = idx / CIN;
  int kw = r % 3; r /= 3;
  int kh = r % 3;
  int co = r / 3;
  float v = FLIP ? w[((ci * COUT + co) * 3 + (2 - kh)) * 3 + (2 - kw)]
                 : w[((co * CIN + ci) * 3 + kh) * 3 + kw];
  wb[idx] = f2bf(v);
}

// el_w (256,4096 k_ref=c*64+s) -> bf16 [n][k_new=(s*64+c)]
__global__ __launch_bounds__(256) void prep_el_k(
    const float* __restrict__ w, unsigned short* __restrict__ wb)
{
  int idx = blockIdx.x * 256 + threadIdx.x;     // < 256*4096
  int kn = idx & 4095, n = idx >> 12;
  wb[idx] = f2bf(w[(size_t)n * 4096 + ((kn & 63) * 64 + (kn >> 6))]);
}

// dl_w (4096,256) row r=c*64+s -> bf16 rows nout=s*64+c
__global__ __launch_bounds__(256) void prep_dl_k(
    const float* __restrict__ w, unsigned short* __restrict__ wb)
{
  int idx = blockIdx.x * 256 + threadIdx.x;     // < 4096*256
  int k = idx & 255, nout = idx >> 8;
  wb[idx] = f2bf(w[(size_t)((nout & 63) * 64 + (nout >> 6)) * 256 + k]);
}

// LSTM weights (10,1024,256) -> bf16 frag-contiguous:
// wb[((l*64+nt)*8+ks)*512 + lane*8 + e] = W[l][nt*16+(lane&15)][ks*32+(lane>>4)*8+e]
__global__ __launch_bounds__(256) void prep_wlstm_k(
    const float* __restrict__ w, unsigned short* __restrict__ wb)
{
  int idx = blockIdx.x * 256 + threadIdx.x;   // exactly 2621440 = 10240 blocks
  int e = idx & 7, lane = (idx >> 3) & 63, ks = (idx >> 9) & 7;
  int nt = (idx >> 12) & 63, l = idx >> 18;
  wb[idx] = f2bf(w[((size_t)l * 1024 + nt * 16 + (lane & 15)) * 256
                   + ks * 32 + (lane >> 4) * 8 + e]);
}

// single-layer (1024x256) bf16 [j][k] -> frag layout (as prep_wlstm, l=0)
__global__ __launch_bounds__(256) void prep_wl1_k(
    const unsigned short* __restrict__ src, unsigned short* __restrict__ wb)
{
  int idx = blockIdx.x * 256 + threadIdx.x;   // 262144 = 1024 blocks
  int e = idx & 7, lane = (idx >> 3) & 63, ks = (idx >> 9) & 7, nt = idx >> 12;
  wb[idx] = src[(size_t)(nt * 16 + (lane & 15)) * 256 + ks * 32 + (lane >> 4) * 8 + e];
}

// fp32 -> bf16 flat cast
__global__ __launch_bounds__(256) void cast_bf16_k(
    const float* __restrict__ src, unsigned short* __restrict__ dst, int count)
{
  int idx = blockIdx.x * 256 + threadIdx.x;
  if (idx < count) dst[idx] = f2bf(src[idx]);
}

// lwT bf16: lwTb[kcol*256 + n] = lw[n*256 + kcol]
__global__ __launch_bounds__(256) void prep_lwt_k(
    const float* __restrict__ lw, unsigned short* __restrict__ lwTb)
{
  int idx = blockIdx.x * 256 + threadIdx.x;   // 65536
  int n = idx & 255, kcol = idx >> 8;
  lwTb[idx] = f2bf(lw[(size_t)n * 256 + kcol]);
}

// beff[j] = sum_n Wih0[j,n]*lb[n] + bih0[j]
__global__ __launch_bounds__(256) void beff_k(
    const float* __restrict__ Wih, const float* __restrict__ lb,
    const float* __restrict__ bih, float* __restrict__ beff)
{
  int j = blockIdx.x * 256 + threadIdx.x;     // < 1024
  float s = bih[j];
  const float* row = Wih + (size_t)j * 256;
  for (int n = 0; n < 256; ++n) s = fmaf(row[n], lb[n], s);
  beff[j] = s;
}

// ---------------------------------------------------------------------------
// ec1: 1ch 64x64 s2 -> 32ch 32x32, NHWC bf16 out. base=chunk img offset.
// ---------------------------------------------------------------------------
__global__ __launch_bounds__(256) void ec1_k(
    const float* __restrict__ x, const float* __restrict__ t,
    const float* __restrict__ w, const float* __restrict__ bias,
    unsigned short* __restrict__ out, int base)
{
  __shared__ float sw[288];
  __shared__ float sb[32];
  for (int i = threadIdx.x; i < 288; i += 256) sw[i] = w[i];
  if (threadIdx.x < 32) sb[threadIdx.x] = bias[threadIdx.x];
  __syncthreads();
  int idx = blockIdx.x * 256 + threadIdx.x;     // < 512*32*32
  int ox = idx & 31, oy = (idx >> 5) & 31, nl = idx >> 10;
  int n = base + nl;
  int b = n >> 5, j = n & 31;
  const float* ip = (j < 16) ? (x + (size_t)(b * 16 + j) * 4096)
                             : (t + (size_t)(b * 16 + j - 16) * 4096);
  float pv[9];
#pragma unroll
  for (int kh = 0; kh < 3; ++kh) {
    int iy = oy * 2 + kh - 1;
#pragma unroll
    for (int kw = 0; kw < 3; ++kw) {
      int ix = ox * 2 + kw - 1;
      pv[kh * 3 + kw] = ((unsigned)iy < 64u && (unsigned)ix < 64u) ? ip[iy * 64 + ix] : 0.f;
    }
  }
  unsigned short u[32];
#pragma unroll
  for (int co = 0; co < 32; ++co) {
    float a = sb[co];
#pragma unroll
    for (int i = 0; i < 9; ++i) a = fmaf(pv[i], sw[co * 9 + i], a);
    u[co] = f2bf(gelu_f(a));
  }
  unsigned short* op = out + (size_t)idx * 32;
#pragma unroll
  for (int p = 0; p < 4; ++p) {
    uint4 v;
    v.x = u[p*8+0] | (u[p*8+1] << 16);
    v.y = u[p*8+2] | (u[p*8+3] << 16);
    v.z = u[p*8+4] | (u[p*8+5] << 16);
    v.w = u[p*8+6] | (u[p*8+7] << 16);
    *(uint4*)&op[p * 8] = v;
  }
}

// ---------------------------------------------------------------------------
// MFMA implicit-GEMM conv. NHWC bf16 in/out. MODE: 0=s1, 1=s2, 2=tconv(ups2).
// ---------------------------------------------------------------------------
template<int CIN, int COUT, int HIN, int WIN, int TH, int TW, int MODE>
__global__ __launch_bounds__(256) void convmf_k(
    const unsigned short* __restrict__ in, const unsigned short* __restrict__ wb,
    const float* __restrict__ bias, unsigned short* __restrict__ out)
{
  constexpr int HO  = (MODE == 1) ? HIN / 2 : (MODE == 2 ? HIN * 2 : HIN);
  constexpr int WO  = (MODE == 1) ? WIN / 2 : (MODE == 2 ? WIN * 2 : WIN);
  constexpr int TIH = (MODE == 1) ? 2 * TH + 1 : TH + 2;
  constexpr int TIW = (MODE == 1) ? 2 * TW + 1 : TW + 2;
  constexpr int CG  = CIN / 8;
  constexpr int K   = 9 * CIN;
  constexpr int KS  = K / 32;
  constexpr int NT  = COUT / 16;
  constexpr int MT  = (TH * TW) / 16;
  constexpr int MPW = MT / 4;
  constexpr int TY  = HO / TH, TX = WO / TW;

  __shared__ unsigned short lds[TIH * TIW * CG * 8];

  const int bid = blockIdx.x;
  const int n = bid / (TY * TX);
  const int trem = bid % (TY * TX);
  const int ty0 = (trem / TX) * TH, tx0 = (trem % TX) * TW;

  constexpr int ENT = TIH * TIW * CG;
  for (int e = threadIdx.x; e < ENT; e += 256) {
    int txx = e % TIW;
    int rr  = e / TIW;
    int cg  = rr % CG;
    int tyy = rr / CG;
    int iy, ix; bool ok;
    if (MODE == 0) {
      iy = ty0 + tyy - 1; ix = tx0 + txx - 1;
      ok = (unsigned)iy < (unsigned)HIN && (unsigned)ix < (unsigned)WIN;
    } else if (MODE == 1) {
      iy = 2 * ty0 + tyy - 1; ix = 2 * tx0 + txx - 1;
      ok = (unsigned)iy < (unsigned)HIN && (unsigned)ix < (unsigned)WIN;
    } else {
      int vy = ty0 + tyy - 1, vx = tx0 + txx - 1;
      ok = vy >= 0 && vx >= 0 && !(vy & 1) && !(vx & 1);
      iy = vy >> 1; ix = vx >> 1;
      ok = ok && iy < HIN && ix < WIN;
    }
    int4 val = {0, 0, 0, 0};
    if (ok) val = *(const int4*)&in[(((size_t)n * HIN + iy) * WIN + ix) * CIN + cg * 8];
    *(int4*)&lds[(size_t)e * 8] = val;
  }
  __syncthreads();

  const int lane = threadIdx.x & 63, wv = threadIdx.x >> 6;
  const int l15 = lane & 15, l4 = lane >> 4;

  f4_t acc[MPW][NT] = {};
  for (int ks = 0; ks < KS; ++ks) {
    const int tap = (ks * 32) / CIN;
    const int kh = tap / 3, kw = tap % 3;
    const int cb = ((ks * 32) % CIN) / 8 + l4;
    bf8_t bf[NT];
#pragma unroll
    for (int nt = 0; nt < NT; ++nt)
      bf[nt] = *(const bf8_t*)&wb[(size_t)(nt * 16 + l15) * K + ks * 32 + 8 * l4];
#pragma unroll
    for (int mi = 0; mi < MPW; ++mi) {
      int m = (wv * MPW + mi) * 16 + l15;
      int oy = m / TW, ox = m % TW;
      int rt = ((MODE == 1) ? 2 * oy : oy) + kh;
      int ct = ((MODE == 1) ? 2 * ox : ox) + kw;
      bf8_t a = *(const bf8_t*)&lds[(((size_t)rt * CG + cb) * TIW + ct) * 8];
#pragma unroll
      for (int nt = 0; nt < NT; ++nt)
        acc[mi][nt] = __builtin_amdgcn_mfma_f32_16x16x32_bf16(a, bf[nt], acc[mi][nt], 0, 0, 0);
    }
  }

#pragma unroll
  for (int mi = 0; mi < MPW; ++mi) {
    int mbase = (wv * MPW + mi) * 16;
#pragma unroll
    for (int nt = 0; nt < NT; ++nt) {
      int co = nt * 16 + l15;
      float bv = bias[co];
#pragma unroll
      for (int r = 0; r < 4; ++r) {
        int m = mbase + l4 * 4 + r;
        int oy = m / TW, ox = m % TW;
        float v = acc[mi][nt][r] + bv;
        out[(((size_t)n * HO + ty0 + oy) * WO + (tx0 + ox)) * COUT + co] = f2bf(gelu_f(v));
      }
    }
  }
}

// ---------------------------------------------------------------------------
// MFMA GEMM: C[m][n] = act(sum_k A[m][k]*B[n][k] + bias).
// BIASMODE: 0 = bias[col], 1 = dl-permuted bias, 2 = no bias.
// ---------------------------------------------------------------------------
template<int BIASMODE, bool GELU, bool OUTBF16>
__global__ __launch_bounds__(256) void gemm16_k(
    const unsigned short* __restrict__ A, const unsigned short* __restrict__ Bw,
    const float* __restrict__ bias, void* __restrict__ Cv, int M, int N, int K)
{
  const int lane = threadIdx.x & 63, wv = threadIdx.x >> 6;
  const int l15 = lane & 15, l4 = lane >> 4;
  const int mbase = blockIdx.y * 64 + wv * 16;
  const int nbase = blockIdx.x * 64;
  f4_t acc[4] = {};
  for (int k0 = 0; k0 < K; k0 += 32) {
    bf8_t a = *(const bf8_t*)&A[(size_t)(mbase + l15) * K + k0 + 8 * l4];
#pragma unroll
    for (int nt = 0; nt < 4; ++nt) {
      bf8_t b = *(const bf8_t*)&Bw[(size_t)(nbase + nt * 16 + l15) * K + k0 + 8 * l4];
      acc[nt] = __builtin_amdgcn_mfma_f32_16x16x32_bf16(a, b, acc[nt], 0, 0, 0);
    }
  }
#pragma unroll
  for (int nt = 0; nt < 4; ++nt) {
    int col = nbase + nt * 16 + l15;
    float bv = 0.f;
    if (BIASMODE == 0) bv = bias[col];
    if (BIASMODE == 1) bv = bias[(col & 63) * 64 + (col >> 6)];
#pragma unroll
    for (int r = 0; r < 4; ++r) {
      int row = mbase + l4 * 4 + r;
      float v = acc[nt][r] + bv;
      if (GELU) v = gelu_f(v);
      if (OUTBF16) ((unsigned short*)Cv)[(size_t)row * N + col] = f2bf(v);
      else         ((float*)Cv)[(size_t)row * N + col] = v;
    }
  }
}

// ---------------------------------------------------------------------------
// dt3 (tconv 32->1) + tanh + fused loss partials. bf16 NHWC in.
// ---------------------------------------------------------------------------
__global__ __launch_bounds__(256) void dt3_loss_k(
    const unsigned short* __restrict__ in,
    const float* __restrict__ w, const float* __restrict__ bias,
    const float* __restrict__ xref, const float* __restrict__ tref,
    float* __restrict__ fout, float* __restrict__ partials, int base)
{
  __shared__ float sw[288];
  for (int i = threadIdx.x; i < 288; i += 256) sw[i] = w[i];
  __syncthreads();
  int idx = blockIdx.x * 256 + threadIdx.x;
  int q = idx & 63, p = (idx >> 6) & 63, nl = idx >> 12;
  int n = base + nl;
  float acc = bias[0];
#pragma unroll
  for (int kh = 0; kh < 3; ++kh) {
    int u = p + kh - 1;
    if (u < 0 || (u & 1) || u >= 64) continue;
#pragma unroll
    for (int kw = 0; kw < 3; ++kw) {
      int v = q + kw - 1;
      if (v < 0 || (v & 1) || v >= 64) continue;
      const unsigned short* row = in + (((size_t)nl * 32 + (u >> 1)) * 32 + (v >> 1)) * 32;
      int wo = (2 - kh) * 3 + (2 - kw);
#pragma unroll
      for (int w2 = 0; w2 < 16; ++w2) {
        unsigned dv = *(const unsigned*)&row[w2 * 2];
        acc = fmaf(__uint_as_float(dv << 16),        sw[(2 * w2) * 9 + wo], acc);
        acc = fmaf(__uint_as_float(dv & 0xffff0000u), sw[(2 * w2 + 1) * 9 + wo], acc);
      }
    }
  }
  float val = tanhf(acc);
  float d;
  int pix = p * 64 + q;
  if (n < 512) {
    fout[(size_t)n * 4096 + pix] = val;
    d = val - tref[(size_t)n * 4096 + pix];
  } else {
    d = val - xref[(size_t)(n - 512) * 4096 + pix];
  }
  __shared__ float red[256];
  red[threadIdx.x] = d * d;
  __syncthreads();
#pragma unroll
  for (int s = 128; s > 0; s >>= 1) {
    if (threadIdx.x < s) red[threadIdx.x] += red[threadIdx.x + s];
    __syncthreads();
  }
  if (threadIdx.x == 0) partials[blockIdx.x] = red[0];
}

__global__ __launch_bounds__(256) void loss_final_k(
    const float* __restrict__ partials, float* __restrict__ out01)
{
  __shared__ float red[256];
  int base = blockIdx.x * 8192;
  float s = 0.f;
  for (int i = threadIdx.x; i < 8192; i += 256) s += partials[base + i];
  red[threadIdx.x] = s;
  __syncthreads();
#pragma unroll
  for (int st = 128; st > 0; st >>= 1) {
    if (threadIdx.x < st) red[threadIdx.x] += red[threadIdx.x + st];
    __syncthreads();
  }
  if (threadIdx.x == 0) out01[blockIdx.x] = red[0] * (1.0f / 2097152.0f);
}

// ---------------------------------------------------------------------------
// LSTM v4: MFMA, 16 blocks x 256 thr (4 waves = 4 gates), M=32 whole batch
// per block, each block owns 16 gate-cols per gate (col0 = bid*16).
// - Phase 1 (t=0..15, teacher-forced): diagonal wavefront, 25 grid barriers.
// - lw-projection folded into phase-2 layer 0 via Meff = Wih0 @ lw,
//   beff = Wih0 @ lb + bih0  ->  phase 2 = 14 timesteps x 10 barriers.
// - h9 snapshots (t=15..30? t=15..29 + final) saved; outs computed post-loop
//   by one GEMM. t=30 cells skipped (out(30) unused by y_t).
// ---------------------------------------------------------------------------
#define LSTM_NB 16

DEV void gridbar(unsigned* bar, unsigned target) {
  __syncthreads();
  if (threadIdx.x == 0) {
    __hip_atomic_fetch_add(bar, 1u, __ATOMIC_RELEASE, __HIP_MEMORY_SCOPE_AGENT);
    unsigned spins = 0;
    while (__hip_atomic_load(bar, __ATOMIC_RELAXED, __HIP_MEMORY_SCOPE_AGENT) < target) {
      __builtin_amdgcn_s_sleep(2);
      if (++spins > (1u << 24)) break;   // safety valve
    }
    (void)__hip_atomic_load(bar, __ATOMIC_ACQUIRE, __HIP_MEMORY_SCOPE_AGENT);
  }
  __syncthreads();
}

__global__ __launch_bounds__(256, 1) void lstm4_k(
    const float* __restrict__ z,              // (1024,256) fp32, row = b*32+t
    const unsigned short* __restrict__ wihb,  // frag-swizzled bf16 (10 layers)
    const unsigned short* __restrict__ whhb,
    const unsigned short* __restrict__ meffb, // frag-swizzled Meff (1 layer)
    const float* __restrict__ bih, const float* __restrict__ bhh,
    const float* __restrict__ beff,
    unsigned short* __restrict__ zbf,     // (16,32,256) bf16 [t][b][k]
    unsigned short* __restrict__ hbf,     // (2,10,32,256) bf16
    unsigned short* __restrict__ h9sav,   // (16,32,256) bf16, slot tt=t-15
    unsigned* __restrict__ bar)
{
  __shared__ float zsm[4 * 32 * 17];    // [gate][row][col16 pad17]
  __shared__ float cls[10 * 32 * 16];   // c state [l][b][j]
  __shared__ float sbias[640];          // bih+bhh [l][g][j]
  __shared__ float sb2[64];             // beff+bhh0 [g][j]

  const int tid = threadIdx.x;
  const int bid = blockIdx.x;           // 0..15
  const int col0 = bid * 16;
  const int lane = tid & 63, g = tid >> 6;      // wave = gate
  const int l15 = lane & 15, l4 = lane >> 4;
  const int gtid = bid * 256 + tid;

  // ---- init ----
  for (int i = gtid; i < 16 * 32 * 256; i += LSTM_NB * 256) {
    int k = i & 255, r = i >> 8;              // dest row r = t*32 + b
    int tt = r >> 5, b = r & 31;
    zbf[i] = f2bf(z[(size_t)(b * 32 + tt) * 256 + k]);
  }
  for (int i = gtid; i < 81920; i += LSTM_NB * 256) hbf[81920 + i] = 0;
  for (int i = tid; i < 5120; i += 256) cls[i] = 0.f;
  for (int i = tid; i < 640; i += 256) {
    int l = i >> 6, gg = (i >> 4) & 3, j = i & 15;
    sbias[i] = bih[l * 1024 + gg * 256 + col0 + j]
             + bhh[l * 1024 + gg * 256 + col0 + j];
  }
  if (tid < 64) {
    int gg = tid >> 4, j = tid & 15;
    sb2[tid] = beff[gg * 256 + col0 + j] + bhh[gg * 256 + col0 + j];
  }

  unsigned ep = 0;
  ++ep; gridbar(bar, ep * LSTM_NB);

  auto cell = [&](int t, int l, bool p2l0) {
    const int cur = t & 1, prv = cur ^ 1;
    const unsigned short* xb =
        p2l0 ? (hbf + (size_t)((prv * 10 + 9) * 32) * 256)
             : ((l == 0) ? (zbf + (size_t)t * 32 * 256)
                         : (hbf + (size_t)((cur * 10 + l - 1) * 32) * 256));
    const unsigned short* hb = hbf + (size_t)((prv * 10 + l) * 32) * 256;
    const unsigned short* wi =
        p2l0 ? (meffb + (size_t)((g * 16 + bid) * 8) * 512)
             : (wihb + (size_t)((l * 64 + g * 16 + bid) * 8) * 512);
    const unsigned short* wh = whhb + (size_t)((l * 64 + g * 16 + bid) * 8) * 512;

    f4_t a0 = {}, a1 = {};
#pragma unroll
    for (int ks = 0; ks < 8; ++ks) {
      bf8_t bv = *(const bf8_t*)&wi[ks * 512 + lane * 8];
      bf8_t av0 = *(const bf8_t*)&xb[(0 * 16 + l15) * 256 + ks * 32 + l4 * 8];
      bf8_t av1 = *(const bf8_t*)&xb[(1 * 16 + l15) * 256 + ks * 32 + l4 * 8];
      a0 = __builtin_amdgcn_mfma_f32_16x16x32_bf16(av0, bv, a0, 0, 0, 0);
      a1 = __builtin_amdgcn_mfma_f32_16x16x32_bf16(av1, bv, a1, 0, 0, 0);
    }
#pragma unroll
    for (int ks = 0; ks < 8; ++ks) {
      bf8_t bv = *(const bf8_t*)&wh[ks * 512 + lane * 8];
      bf8_t av0 = *(const bf8_t*)&hb[(0 * 16 + l15) * 256 + ks * 32 + l4 * 8];
      bf8_t av1 = *(const bf8_t*)&hb[(1 * 16 + l15) * 256 + ks * 32 + l4 * 8];
      a0 = __builtin_amdgcn_mfma_f32_16x16x32_bf16(av0, bv, a0, 0, 0, 0);
      a1 = __builtin_amdgcn_mfma_f32_16x16x32_bf16(av1, bv, a1, 0, 0, 0);
    }
#pragma unroll
    for (int r = 0; r < 4; ++r) {
      zsm[(g * 32 + l4 * 4 + r) * 17 + l15] = a0[r];
      zsm[(g * 32 + 16 + l4 * 4 + r) * 17 + l15] = a1[r];
    }
    __syncthreads();
    // gate math: 32 rows x 16 cols = 512 elems, 2 per thread
#pragma unroll
    for (int half = 0; half < 2; ++half) {
      int e = tid + half * 256;
      int b = e >> 4, j = e & 15;
      float bi_, bf_, bg_, bo_;
      if (p2l0) { bi_ = sb2[j]; bf_ = sb2[16 + j]; bg_ = sb2[32 + j]; bo_ = sb2[48 + j]; }
      else {
        bi_ = sbias[l * 64 + j];      bf_ = sbias[l * 64 + 16 + j];
        bg_ = sbias[l * 64 + 32 + j]; bo_ = sbias[l * 64 + 48 + j];
      }
      float zi = zsm[(0 * 32 + b) * 17 + j] + bi_;
      float zf = zsm[(1 * 32 + b) * 17 + j] + bf_;
      float zg = zsm[(2 * 32 + b) * 17 + j] + bg_;
      float zo = zsm[(3 * 32 + b) * 17 + j] + bo_;
      float cold = cls[(l * 32 + b) * 16 + j];
      float cn = sigm_f(zf) * cold + sigm_f(zi) * tanhf(zg);
      cls[(l * 32 + b) * 16 + j] = cn;
      float hn = sigm_f(zo) * tanhf(cn);
      unsigned short hv = f2bf(hn);
      hbf[(size_t)(((t & 1) * 10 + l) * 32 + b) * 256 + col0 + j] = hv;
      if (l == 9 && t >= 15) h9sav[(size_t)((t - 15) * 32 + b) * 256 + col0 + j] = hv;
    }
    __syncthreads();
  };

  // ---- phase 1: diagonal wavefront over (t,l), t<=15 ----
  for (int d = 0; d <= 24; ++d) {
    int tlo = d - 9 > 0 ? d - 9 : 0;
    int thi = d < 15 ? d : 15;
    for (int t = tlo; t <= thi; ++t) cell(t, d - t, false);
    ++ep; gridbar(bar, ep * LSTM_NB);
  }
  // ---- phase 2: serial, out-projection folded into l=0 ----
  for (int t = 16; t <= 29; ++t) {
    for (int l = 0; l < 10; ++l) {
      cell(t, l, l == 0);
      ++ep; gridbar(bar, ep * LSTM_NB);
    }
  }
}

// ---------------------------------------------------------------------------
// Decoder input gather -> bf16: rows 0..511 = y_t, rows 512..1023 = z_x
// ---------------------------------------------------------------------------
__global__ __launch_bounds__(256) void gather_dec_k(
    const float* __restrict__ outs, const float* __restrict__ z,
    unsigned short* __restrict__ ydec)
{
  int idx = blockIdx.x * 256 + threadIdx.x;   // < 262144
  int rrow = idx >> 8, k = idx & 255;
  float v;
  if (rrow < 512) {
    int b = rrow >> 4, i = rrow & 15;
    v = outs[(size_t)((15 + i) * 32 + b) * 256 + k];
  } else {
    int rr = rrow - 512;
    int b = rr >> 4, tt = rr & 15;
    v = z[(size_t)(b * 32 + tt) * 256 + k];
  }
  ydec[idx] = f2bf(v);
}

// ---------------------------------------------------------------------------
extern "C" void kernel_launch(void* const* d_in, const int* in_sizes, int n_in,
                              void* d_out, int out_size, void* d_ws, size_t ws_size,
                              hipStream_t stream) {
  const float* x     = (const float*)d_in[0];
  const float* t     = (const float*)d_in[1];
  const float* ec1_w = (const float*)d_in[2];
  const float* ec1_b = (const float*)d_in[3];
  const float* ec2_w = (const float*)d_in[4];
  const float* ec2_b = (const float*)d_in[5];
  const float* ec3_w = (const float*)d_in[6];
  const float* ec3_b = (const float*)d_in[7];
  const float* ec4_w = (const float*)d_in[8];
  const float* ec4_b = (const float*)d_in[9];
  const float* ec5_w = (const float*)d_in[10];
  const float* ec5_b = (const float*)d_in[11];
  const float* el_w  = (const float*)d_in[12];
  const float* el_b  = (const float*)d_in[13];
  const float* dl_w  = (const float*)d_in[14];
  const float* dl_b  = (const float*)d_in[15];
  const float* dt1_w = (const float*)d_in[16];
  const float* dt1_b = (const float*)d_in[17];
  const float* dc1_w = (const float*)d_in[18];
  const float* dc1_b = (const float*)d_in[19];
  const float* dt2_w = (const float*)d_in[20];
  const float* dt2_b = (const float*)d_in[21];
  const float* dc2_w = (const float*)d_in[22];
  const float* dc2_b = (const float*)d_in[23];
  const float* dt3_w = (const float*)d_in[24];
  const float* dt3_b = (const float*)d_in[25];
  const float* Wih   = (const float*)d_in[26];
  const float* Whh   = (const float*)d_in[27];
  const float* bih   = (const float*)d_in[28];
  const float* bhh   = (const float*)d_in[29];
  const float* lw    = (const float*)d_in[30];
  const float* lb    = (const float*)d_in[31];
  float* out = (float*)d_out;

  char* base = (char*)d_ws;
  size_t off = 0;
  auto alloc = [&](size_t bytes) -> char* {
    char* p = base + off;
    off += (bytes + 255) & ~(size_t)255;
    return p;
  };
  typedef unsigned short us;
  unsigned* bar   = (unsigned*)alloc(256);
  float* zbuf     = (float*)alloc((size_t)1024 * 256 * 4);
  float* outsbuf  = (float*)alloc((size_t)31 * 32 * 256 * 4);
  us*    zbf      = (us*)alloc((size_t)16 * 32 * 256 * 2);
  us*    hbf      = (us*)alloc((size_t)2 * 10 * 32 * 256 * 2);
  us*    h9sav    = (us*)alloc((size_t)16 * 32 * 256 * 2);
  us*    ydec     = (us*)alloc((size_t)1024 * 256 * 2);
  float* partials = (float*)alloc((size_t)16384 * 4);
  us* wb_ec2 = (us*)alloc((size_t)32 * 288 * 2);
  us* wb_ec3 = (us*)alloc((size_t)64 * 288 * 2);
  us* wb_ec4 = (us*)alloc((size_t)64 * 576 * 2);
  us* wb_ec5 = (us*)alloc((size_t)64 * 576 * 2);
  us* wb_dt1 = (us*)alloc((size_t)64 * 576 * 2);
  us* wb_dc1 = (us*)alloc((size_t)64 * 576 * 2);
  us* wb_dt2 = (us*)alloc((size_t)32 * 576 * 2);
  us* wb_dc2 = (us*)alloc((size_t)32 * 288 * 2);
  us* elWb   = (us*)alloc((size_t)256 * 4096 * 2);
  us* dlWb   = (us*)alloc((size_t)4096 * 256 * 2);
  us* wihb   = (us*)alloc((size_t)10 * 1024 * 256 * 2);      // 5 MB
  us* whhb   = (us*)alloc((size_t)10 * 1024 * 256 * 2);      // 5 MB
  us* wih0b  = (us*)alloc((size_t)1024 * 256 * 2);
  us* lwTb   = (us*)alloc((size_t)256 * 256 * 2);
  us* lwbp   = (us*)alloc((size_t)256 * 256 * 2);
  us* meffp  = (us*)alloc((size_t)1024 * 256 * 2);
  us* meffb  = (us*)alloc((size_t)1024 * 256 * 2);
  float* beff = (float*)alloc((size_t)1024 * 4);
  us* enc5   = (us*)alloc((size_t)1024 * 4096 * 2);          // 8.4 MB
  us* bufA   = (us*)alloc((size_t)512 * 32 * 32 * 32 * 2);   // 33.5 MB
  us* bufB   = (us*)alloc((size_t)512 * 32 * 32 * 32 * 2);   // 33.5 MB
  (void)in_sizes; (void)n_in; (void)out_size; (void)ws_size;

  hipMemsetAsync(bar, 0, 16, stream);

  // ---- weight prep ----
  prepw_k<<<(32*32*9+255)/256, 256, 0, stream>>>(ec2_w, wb_ec2, 32, 32, 0);
  prepw_k<<<(64*32*9+255)/256, 256, 0, stream>>>(ec3_w, wb_ec3, 64, 32, 0);
  prepw_k<<<(64*64*9+255)/256, 256, 0, stream>>>(ec4_w, wb_ec4, 64, 64, 0);
  prepw_k<<<(64*64*9+255)/256, 256, 0, stream>>>(ec5_w, wb_ec5, 64, 64, 0);
  prepw_k<<<(64*64*9+255)/256, 256, 0, stream>>>(dt1_w, wb_dt1, 64, 64, 1);
  prepw_k<<<(64*64*9+255)/256, 256, 0, stream>>>(dc1_w, wb_dc1, 64, 64, 0);
  prepw_k<<<(32*64*9+255)/256, 256, 0, stream>>>(dt2_w, wb_dt2, 32, 64, 1);
  prepw_k<<<(32*32*9+255)/256, 256, 0, stream>>>(dc2_w, wb_dc2, 32, 32, 0);
  prep_el_k<<<4096, 256, 0, stream>>>(el_w, elWb);
  prep_dl_k<<<4096, 256, 0, stream>>>(dl_w, dlWb);
  prep_wlstm_k<<<10240, 256, 0, stream>>>(Wih, wihb);
  prep_wlstm_k<<<10240, 256, 0, stream>>>(Whh, whhb);
  // Meff = Wih0 @ lw (1024x256), beff = Wih0 @ lb + bih0
  cast_bf16_k<<<1024, 256, 0, stream>>>(Wih, wih0b, 262144);
  prep_lwt_k<<<256, 256, 0, stream>>>(lw, lwTb);
  cast_bf16_k<<<256, 256, 0, stream>>>(lw, lwbp, 65536);
  gemm16_k<2, false, true><<<dim3(4, 16), 256, 0, stream>>>(wih0b, lwTb, lb, meffp, 1024, 256, 256);
  prep_wl1_k<<<1024, 256, 0, stream>>>(meffp, meffb);
  beff_k<<<4, 256, 0, stream>>>(Wih, lb, bih, beff);

  // ---- encoder: 2 chunks of 512 images ----
  for (int ch = 0; ch < 2; ++ch) {
    ec1_k<<<2048, 256, 0, stream>>>(x, t, ec1_w, ec1_b, bufA, ch * 512);
    convmf_k<32, 32, 32, 32, 32, 32, 0><<<512, 256, 0, stream>>>(bufA, wb_ec2, ec2_b, bufB);
    convmf_k<32, 64, 32, 32, 16, 16, 1><<<512, 256, 0, stream>>>(bufB, wb_ec3, ec3_b, bufA);
    convmf_k<64, 64, 16, 16, 16, 16, 0><<<512, 256, 0, stream>>>(bufA, wb_ec4, ec4_b, bufB);
    convmf_k<64, 64, 16, 16, 8, 8, 1><<<512, 256, 0, stream>>>(bufB, wb_ec5, ec5_b,
                                                               enc5 + (size_t)ch * 512 * 4096);
  }
  gemm16_k<0, false, false><<<dim3(4, 16), 256, 0, stream>>>(enc5, elWb, el_b, zbuf, 1024, 256, 4096);

  // ---- LSTM (MFMA, 16 blocks, 166 grid barriers) ----
  lstm4_k<<<LSTM_NB, 256, 0, stream>>>(zbuf, wihb, whhb, meffb, bih, bhh, beff,
                                       zbf, hbf, h9sav, bar);
  // outs[t=15..30] = h9sav @ lw^T + lb  (t=30 row = garbage, unused)
  gemm16_k<0, false, false><<<dim3(4, 8), 256, 0, stream>>>(
      h9sav, lwbp, lb, outsbuf + (size_t)15 * 32 * 256, 512, 256, 256);

  // ---- decoder: 2 chunks of 512 rows (chunk0 = pred, chunk1 = rec) ----
  gather_dec_k<<<1024, 256, 0, stream>>>(outsbuf, zbuf, ydec);
  for (int ch = 0; ch < 2; ++ch) {
    gemm16_k<1, true, true><<<dim3(64, 8), 256, 0, stream>>>(
        ydec + (size_t)ch * 512 * 256, dlWb, dl_b, bufB, 512, 4096, 256);
    convmf_k<64, 64, 8, 8, 16, 16, 2><<<512, 256, 0, stream>>>(bufB, wb_dt1, dt1_b, bufA);
    convmf_k<64, 64, 16, 16, 16, 16, 0><<<512, 256, 0, stream>>>(bufA, wb_dc1, dc1_b, bufB);
    convmf_k<64, 32, 16, 16, 16, 32, 2><<<1024, 256, 0, stream>>>(bufB, wb_dt2, dt2_b, bufA);
    convmf_k<32, 32, 32, 32, 32, 32, 0><<<512, 256, 0, stream>>>(bufA, wb_dc2, dc2_b, bufB);
    dt3_loss_k<<<8192, 256, 0, stream>>>(bufB, dt3_w, dt3_b, x, t, out + 2,
                                         partials + ch * 8192, ch * 512);
  }
  loss_final_k<<<2, 256, 0, stream>>>(partials, out);
}